// Round 1
// baseline (1769.408 us; speedup 1.0000x reference)
//
#include <hip/hip_runtime.h>
#include <cstddef>

#define LPIX 576
#define CCH  2048
#define NB   4

// ---------------- generic tiled fp32 GEMM ----------------
// Y[b][o][l] = sum_c W[o][c] * X[b][c][l] + bias[o]
// MODE 1: Y = (acc+bias) * S[b][l] + PT[b][o][l]
template<int MODE>
__global__ __launch_bounds__(256) void gemm_k(
    const float* __restrict__ W, const float* __restrict__ bias,
    const float* __restrict__ X, int xbstride,
    float* __restrict__ Y, int ybstride, int Cin,
    const float* __restrict__ S, const float* __restrict__ PT)
{
    __shared__ float As[16][65];
    __shared__ float Bs[16][64];
    const int b  = blockIdx.z;
    const int o0 = blockIdx.y * 64;
    const int l0 = blockIdx.x * 64;
    const float* Xb = X + (size_t)b * xbstride;
    float* Yb = Y + (size_t)b * ybstride;
    const int tx = threadIdx.x, ty = threadIdx.y;
    const int tid = ty * 16 + tx;
    const int arow = tid >> 2;          // 0..63
    const int ac4  = (tid & 3) * 4;     // 0,4,8,12
    const int brow = tid >> 4;          // 0..15
    const int bc4  = (tid & 15) * 4;    // 0..60

    float acc[4][4] = {};

    for (int c0 = 0; c0 < Cin; c0 += 16) {
        float4 wv = *(const float4*)(W + (size_t)(o0 + arow) * Cin + c0 + ac4);
        As[ac4 + 0][arow] = wv.x;
        As[ac4 + 1][arow] = wv.y;
        As[ac4 + 2][arow] = wv.z;
        As[ac4 + 3][arow] = wv.w;
        float4 xv = *(const float4*)(Xb + (size_t)(c0 + brow) * LPIX + l0 + bc4);
        *(float4*)(&Bs[brow][bc4]) = xv;
        __syncthreads();
        #pragma unroll
        for (int kk = 0; kk < 16; ++kk) {
            float a0 = As[kk][ty*4+0], a1 = As[kk][ty*4+1];
            float a2 = As[kk][ty*4+2], a3 = As[kk][ty*4+3];
            float b0 = Bs[kk][tx*4+0], b1 = Bs[kk][tx*4+1];
            float b2 = Bs[kk][tx*4+2], b3 = Bs[kk][tx*4+3];
            acc[0][0] += a0*b0; acc[0][1] += a0*b1; acc[0][2] += a0*b2; acc[0][3] += a0*b3;
            acc[1][0] += a1*b0; acc[1][1] += a1*b1; acc[1][2] += a1*b2; acc[1][3] += a1*b3;
            acc[2][0] += a2*b0; acc[2][1] += a2*b1; acc[2][2] += a2*b2; acc[2][3] += a2*b3;
            acc[3][0] += a3*b0; acc[3][1] += a3*b1; acc[3][2] += a3*b2; acc[3][3] += a3*b3;
        }
        __syncthreads();
    }
    #pragma unroll
    for (int i = 0; i < 4; ++i) {
        const int o = o0 + ty*4 + i;
        const float bi = bias[o];
        #pragma unroll
        for (int j = 0; j < 4; ++j) {
            const int l = l0 + tx*4 + j;
            float v = acc[i][j] + bi;
            if constexpr (MODE == 1) {
                v = v * S[b*LPIX + l] + PT[((size_t)b*CCH + o)*LPIX + l];
            }
            Yb[(size_t)o*LPIX + l] = v;
        }
    }
}

// ---------------- per-batch Gram M[lr][lt] = sum_c K[c][lr]*Q[c][lt] ----------------
__global__ __launch_bounds__(256) void gram_k(
    const float* __restrict__ K, int kbstride,
    const float* __restrict__ Q, int qbstride,
    float* __restrict__ M)
{
    __shared__ float Ks[16][64];
    __shared__ float Qs[16][64];
    const int b  = blockIdx.z;
    const int r0 = blockIdx.y * 64;
    const int t0 = blockIdx.x * 64;
    const float* Kb = K + (size_t)b * kbstride;
    const float* Qb = Q + (size_t)b * qbstride;
    const int tx = threadIdx.x, ty = threadIdx.y;
    const int tid = ty * 16 + tx;
    const int row  = tid >> 4;         // 0..15
    const int col4 = (tid & 15) * 4;   // 0..60

    float acc[4][4] = {};

    for (int c0 = 0; c0 < CCH; c0 += 16) {
        *(float4*)(&Ks[row][col4]) = *(const float4*)(Kb + (size_t)(c0 + row) * LPIX + r0 + col4);
        *(float4*)(&Qs[row][col4]) = *(const float4*)(Qb + (size_t)(c0 + row) * LPIX + t0 + col4);
        __syncthreads();
        #pragma unroll
        for (int kk = 0; kk < 16; ++kk) {
            float a0 = Ks[kk][ty*4+0], a1 = Ks[kk][ty*4+1];
            float a2 = Ks[kk][ty*4+2], a3 = Ks[kk][ty*4+3];
            float b0 = Qs[kk][tx*4+0], b1 = Qs[kk][tx*4+1];
            float b2 = Qs[kk][tx*4+2], b3 = Qs[kk][tx*4+3];
            acc[0][0] += a0*b0; acc[0][1] += a0*b1; acc[0][2] += a0*b2; acc[0][3] += a0*b3;
            acc[1][0] += a1*b0; acc[1][1] += a1*b1; acc[1][2] += a1*b2; acc[1][3] += a1*b3;
            acc[2][0] += a2*b0; acc[2][1] += a2*b1; acc[2][2] += a2*b2; acc[2][3] += a2*b3;
            acc[3][0] += a3*b0; acc[3][1] += a3*b1; acc[3][2] += a3*b2; acc[3][3] += a3*b3;
        }
        __syncthreads();
    }
    float* Mb = M + (size_t)b * LPIX * LPIX;
    #pragma unroll
    for (int i = 0; i < 4; ++i)
        #pragma unroll
        for (int j = 0; j < 4; ++j)
            Mb[(size_t)(r0 + ty*4 + i) * LPIX + t0 + tx*4 + j] = acc[i][j];
}

// ---------------- per-pixel squared channel norms ----------------
__global__ __launch_bounds__(256) void sqnorm_k(
    const float* __restrict__ K, const float* __restrict__ Q2,
    float* __restrict__ nk, float* __restrict__ nq)
{
    const int b = blockIdx.y;
    const int l = blockIdx.x * 64 + threadIdx.x;
    const int ty = threadIdx.y;
    const float* src = (blockIdx.z == 0) ? (K + (size_t)b * CCH * LPIX)
                                         : (Q2 + (size_t)b * 4096 * LPIX);
    float s = 0.f;
    for (int c = ty; c < CCH; c += 4) {
        float v = src[(size_t)c * LPIX + l];
        s += v * v;
    }
    __shared__ float red[4][64];
    red[ty][threadIdx.x] = s;
    __syncthreads();
    if (ty == 0) {
        s = red[0][threadIdx.x] + red[1][threadIdx.x] + red[2][threadIdx.x] + red[3][threadIdx.x];
        ((blockIdx.z == 0) ? nk : nq)[b * LPIX + l] = s;
    }
}

// ---------------- 3x3 box filter + inverse sqrt of patch norms ----------------
__global__ void boxinv_k(const float* __restrict__ nk, const float* __restrict__ nq,
                         float* __restrict__ invNk, float* __restrict__ invNq)
{
    int idx = blockIdx.x * 256 + threadIdx.x;
    if (idx >= 2 * NB * LPIX) return;
    int map = idx / (NB * LPIX);
    int rem = idx % (NB * LPIX);
    int b = rem / LPIX, l = rem % LPIX;
    int i = l / 24, j = l % 24;
    const float* src = map ? nq : nk;
    float s = 0.f;
    for (int di = -1; di <= 1; ++di)
        for (int dj = -1; dj <= 1; ++dj) {
            int ii = i + di, jj = j + dj;
            if (ii >= 0 && ii < 24 && jj >= 0 && jj < 24)
                s += src[b * LPIX + ii * 24 + jj];
        }
    float n = fmaxf(sqrtf(s), 1e-12f);
    (map ? invNq : invNk)[b * LPIX + l] = 1.0f / n;
}

// ---------------- dj pass: diagonal +-1 shift with column masks ----------------
__global__ void shiftdj_k(const float* __restrict__ M, float* __restrict__ A)
{
    int idx = blockIdx.x * 256 + threadIdx.x;
    int b  = idx / (LPIX * LPIX);
    int rem = idx % (LPIX * LPIX);
    int lr = rem / LPIX, lt = rem % LPIX;
    int jr = lr % 24, jt = lt % 24;
    const float* Mb = M + (size_t)b * LPIX * LPIX;
    float s = Mb[(size_t)lr * LPIX + lt];
    if (jr > 0 && jt > 0)   s += Mb[(size_t)(lr - 1) * LPIX + lt - 1];
    if (jr < 23 && jt < 23) s += Mb[(size_t)(lr + 1) * LPIX + lt + 1];
    A[idx] = s;
}

// ---------------- di pass fused with argmax over l_ref ----------------
__global__ __launch_bounds__(256) void argmax_k(
    const float* __restrict__ A,
    const float* __restrict__ invNk, const float* __restrict__ invNq,
    float* __restrict__ S, int* __restrict__ Arg)
{
    const int b = blockIdx.y;
    const int tx = threadIdx.x, ty = threadIdx.y;
    const int lt = blockIdx.x * 64 + tx;
    const int it = lt / 24;
    const float* Ab = A + (size_t)b * LPIX * LPIX;
    float best = -1e30f; int bidx = 0;
    for (int lr = ty; lr < LPIX; lr += 4) {
        int ir = lr / 24;
        float g = Ab[(size_t)lr * LPIX + lt];
        if (ir > 0 && it > 0)   g += Ab[(size_t)(lr - 24) * LPIX + lt - 24];
        if (ir < 23 && it < 23) g += Ab[(size_t)(lr + 24) * LPIX + lt + 24];
        float v = g * invNk[b * LPIX + lr];
        if (v > best) { best = v; bidx = lr; }
    }
    __shared__ float rv[4][64];
    __shared__ int   ri[4][64];
    rv[ty][tx] = best; ri[ty][tx] = bidx;
    __syncthreads();
    if (ty == 0) {
        for (int y = 1; y < 4; ++y) {
            float v = rv[y][tx]; int id = ri[y][tx];
            if (v > best || (v == best && id < bidx)) { best = v; bidx = id; }
        }
        S[b * LPIX + lt]   = best * invNq[b * LPIX + lt];
        Arg[b * LPIX + lt] = bidx;
    }
}

// ---------------- gather best ref patches + fold (overlap-add /9) ----------------
__global__ __launch_bounds__(256) void gather_k(
    const float* __restrict__ K, const int* __restrict__ Arg,
    float* __restrict__ X2)
{
    const int b  = blockIdx.z;
    const int l0 = blockIdx.x * 64;
    const int c0 = blockIdx.y * 16;
    const int tx = threadIdx.x, ty = threadIdx.y;
    const int tid = ty * 64 + tx;
    __shared__ int tap[64][9];
    for (int e = tid; e < 64 * 9; e += 256) {
        int px = e / 9, t9 = e % 9;
        int l = l0 + px;
        int i = l / 24, j = l % 24;
        int ki = t9 / 3, kj = t9 % 3;
        int ip = i + 1 - ki, jp = j + 1 - kj;
        int off = -1;
        if (ip >= 0 && ip < 24 && jp >= 0 && jp < 24) {
            int a = Arg[b * LPIX + ip * 24 + jp];
            int rr = a / 24 + ki - 1;
            int cc = a % 24 + kj - 1;
            if (rr >= 0 && rr < 24 && cc >= 0 && cc < 24) off = rr * 24 + cc;
        }
        tap[px][t9] = off;
    }
    __syncthreads();
    const float* Kb = K + (size_t)b * CCH * LPIX;
    const int l = l0 + tx;
    #pragma unroll
    for (int u = 0; u < 4; ++u) {
        int c = c0 + ty * 4 + u;
        const float* Kc = Kb + (size_t)c * LPIX;
        float s = 0.f;
        #pragma unroll
        for (int t9 = 0; t9 < 9; ++t9) {
            int off = tap[tx][t9];
            if (off >= 0) s += Kc[off];
        }
        X2[((size_t)b * 4096 + 2048 + c) * LPIX + l] = s * (1.0f / 9.0f);
    }
}

extern "C" void kernel_launch(void* const* d_in, const int* in_sizes, int n_in,
                              void* d_out, int out_size, void* d_ws, size_t ws_size,
                              hipStream_t stream) {
    const float* part_ref = (const float*)d_in[0];
    const float* part_tgt = (const float*)d_in[1];
    const float* wq = (const float*)d_in[2];
    const float* bq = (const float*)d_in[3];
    const float* wk = (const float*)d_in[4];
    const float* bk = (const float*)d_in[5];
    const float* wt = (const float*)d_in[6];
    const float* bt = (const float*)d_in[7];
    float* out = (float*)d_out;

    // workspace layout (floats); total ~16.8M floats ~= 67 MB
    float* x2    = (float*)d_ws;                       // B*4096*L (q first half, T_part second)
    float* kbuf  = x2    + (size_t)NB * 4096 * LPIX;   // B*2048*L
    float* Mbuf  = kbuf  + (size_t)NB * CCH  * LPIX;   // B*L*L
    float* Abuf  = Mbuf  + (size_t)NB * LPIX * LPIX;   // B*L*L
    float* nkraw = Abuf  + (size_t)NB * LPIX * LPIX;
    float* nqraw = nkraw + NB * LPIX;
    float* invNk = nqraw + NB * LPIX;
    float* invNq = invNk + NB * LPIX;
    float* Sbuf  = invNq + NB * LPIX;
    int*   Arg   = (int*)(Sbuf + NB * LPIX);

    dim3 gblk(16, 16);
    // q = wq @ part_target + bq  -> x2 first half
    gemm_k<0><<<dim3(9, 32, NB), gblk, 0, stream>>>(wq, bq, part_tgt, CCH * LPIX,
                                                    x2, 4096 * LPIX, CCH, nullptr, nullptr);
    // k = wk @ part_ref + bk
    gemm_k<0><<<dim3(9, 32, NB), gblk, 0, stream>>>(wk, bk, part_ref, CCH * LPIX,
                                                    kbuf, CCH * LPIX, CCH, nullptr, nullptr);
    // per-pixel squared norms of k (z=0) and q (z=1)
    sqnorm_k<<<dim3(9, NB, 2), dim3(64, 4), 0, stream>>>(kbuf, x2, nkraw, nqraw);
    // 3x3 box + rsqrt
    boxinv_k<<<dim3(18), dim3(256), 0, stream>>>(nkraw, nqraw, invNk, invNq);
    // M = k^T q per batch
    gram_k<<<dim3(9, 9, NB), gblk, 0, stream>>>(kbuf, CCH * LPIX, x2, 4096 * LPIX, Mbuf);
    // dj diagonal aggregation
    shiftdj_k<<<dim3(NB * LPIX * LPIX / 256), dim3(256), 0, stream>>>(Mbuf, Abuf);
    // di aggregation fused with normalized argmax
    argmax_k<<<dim3(9, NB), dim3(64, 4), 0, stream>>>(Abuf, invNk, invNq, Sbuf, Arg);
    // gather best patches, fold /9 -> x2 second half
    gather_k<<<dim3(9, 128, NB), dim3(64, 4), 0, stream>>>(kbuf, Arg, x2);
    // res = (wt @ [q;T_part] + bt) * S + part_target
    gemm_k<1><<<dim3(9, 32, NB), gblk, 0, stream>>>(wt, bt, x2, 4096 * LPIX,
                                                    out, CCH * LPIX, 4096, Sbuf, part_tgt);
}

// Round 2
// 699.926 us; speedup vs baseline: 2.5280x; 2.5280x over previous
//
#include <hip/hip_runtime.h>
#include <cstddef>
#include <cstdint>

#define LPIX 576
#define LPAD 640
#define CCH  2048
#define NB   4

typedef __attribute__((ext_vector_type(8))) short short8;
typedef __attribute__((ext_vector_type(4))) float f32x4;
typedef __attribute__((ext_vector_type(4))) unsigned short u16x4;

__device__ __forceinline__ unsigned short f2bf(float f) {
    uint32_t u = __builtin_bit_cast(uint32_t, f);
    u += 0x7fff + ((u >> 16) & 1);          // round-to-nearest-even
    return (unsigned short)(u >> 16);
}
__device__ __forceinline__ float bf2f(unsigned short s) {
    return __builtin_bit_cast(float, (uint32_t)s << 16);
}

__device__ __forceinline__ void gload_lds16(const void* g, void* l) {
    __builtin_amdgcn_global_load_lds((const __attribute__((address_space(1))) void*)g,
                                     (__attribute__((address_space(3))) void*)l, 16, 0, 0);
}

// ---------------- weight cast fp32 -> bf16 (same layout) ----------------
__global__ __launch_bounds__(256) void wcast_k(const float* __restrict__ W,
                                               short* __restrict__ Wb, int n) {
    int i = (blockIdx.x * 256 + threadIdx.x) * 4;
    if (i >= n) return;
    float4 v = *(const float4*)(W + i);
    u16x4 u;
    u.x = f2bf(v.x); u.y = f2bf(v.y); u.z = f2bf(v.z); u.w = f2bf(v.w);
    *(u16x4*)(Wb + i) = u;
}

// ---------------- transpose-cast: X[b][c][l] fp32 -> T[b][l][c] bf16, l padded to 640, pad=0 ----
__global__ __launch_bounds__(256) void tcast_k(const float* __restrict__ X,
                                               short* __restrict__ T) {
    __shared__ float tile[32][33];
    const int b = blockIdx.z;
    const int c0 = blockIdx.y * 32;
    const int l0 = blockIdx.x * 32;
    const int tx = threadIdx.x, ty = threadIdx.y;
    #pragma unroll
    for (int j = 0; j < 4; ++j) {
        int c = c0 + ty + j * 8;
        int l = l0 + tx;
        float v = 0.f;
        if (l < LPIX) v = X[((size_t)b * CCH + c) * LPIX + l];
        tile[ty + j * 8][tx] = v;
    }
    __syncthreads();
    #pragma unroll
    for (int j = 0; j < 4; ++j) {
        int l = l0 + ty + j * 8;
        int c = c0 + tx;
        T[((size_t)b * LPAD + l) * CCH + c] = (short)f2bf(tile[tx][ty + j * 8]);
    }
}

// ---------------- MFMA GEMM: D[m][n] = sum_k A[m][k]*B[n][k]  (both k-contiguous bf16) ----
// EPI 0: conv  -> bf16 out, += bias[n], no mask
// EPI 1: gram  -> fp32 out, mask m<mlim && n<nlim
// EPI 2: final -> fp32 out, += bias[m], *S[n], += PT[m][n], mask n<nlim
template<int EPI>
__global__ __launch_bounds__(256) void mmbt_k(
    const short* __restrict__ A, int lda, size_t abstride,
    const short* __restrict__ B, int ldb, size_t bbstride,
    int K,
    void* __restrict__ Y, int ldy, size_t ybstride, int mlim, int nlim,
    const float* __restrict__ bias,
    const float* __restrict__ S, const float* __restrict__ PT)
{
    __shared__ short As[128 * 32];
    __shared__ short Bs[128 * 32];
    const int b  = blockIdx.z;
    const int m0 = blockIdx.y * 128;
    const int n0 = blockIdx.x * 128;
    const short* Ab = A + (size_t)b * abstride;
    const short* Bb = B + (size_t)b * bbstride;
    const int tid  = threadIdx.x;
    const int lane = tid & 63;
    const int w    = tid >> 6;
    // staging: chunk c handled as lds element offset c*8; row=c>>2, koff=(c&3)*8
    const int r1 = tid >> 2;
    const int k1 = (tid & 3) * 8;
    const int wm = (w & 1) * 64;
    const int wn = (w >> 1) * 64;
    const int l15 = lane & 15;
    const int quad = lane >> 4;
    const int k8 = quad * 8;

    f32x4 acc[4][4] = {};

    const short* Asrc1 = Ab + (size_t)(m0 + r1) * lda + k1;
    const short* Asrc2 = Ab + (size_t)(m0 + r1 + 64) * lda + k1;
    const short* Bsrc1 = Bb + (size_t)(n0 + r1) * ldb + k1;
    const short* Bsrc2 = Bb + (size_t)(n0 + r1 + 64) * ldb + k1;
    short* ldsA1 = As + tid * 8;
    short* ldsA2 = As + (tid + 256) * 8;
    short* ldsB1 = Bs + tid * 8;
    short* ldsB2 = Bs + (tid + 256) * 8;

    for (int c0 = 0; c0 < K; c0 += 32) {
        gload_lds16(Asrc1 + c0, ldsA1);
        gload_lds16(Asrc2 + c0, ldsA2);
        gload_lds16(Bsrc1 + c0, ldsB1);
        gload_lds16(Bsrc2 + c0, ldsB2);
        __syncthreads();   // drains vmcnt before barrier (compiler-inserted)
        short8 fa[4], fb[4];
        #pragma unroll
        for (int i = 0; i < 4; ++i)
            fa[i] = *(const short8*)(As + (wm + i * 16 + l15) * 32 + k8);
        #pragma unroll
        for (int i = 0; i < 4; ++i)
            fb[i] = *(const short8*)(Bs + (wn + i * 16 + l15) * 32 + k8);
        #pragma unroll
        for (int i = 0; i < 4; ++i)
            #pragma unroll
            for (int j = 0; j < 4; ++j)
                acc[i][j] = __builtin_amdgcn_mfma_f32_16x16x32_bf16(fa[i], fb[j], acc[i][j], 0, 0, 0);
        __syncthreads();
    }

    #pragma unroll
    for (int i = 0; i < 4; ++i) {
        #pragma unroll
        for (int j = 0; j < 4; ++j) {
            const int gn = n0 + wn + j * 16 + l15;
            #pragma unroll
            for (int r = 0; r < 4; ++r) {
                const int gm = m0 + wm + i * 16 + quad * 4 + r;
                float v = acc[i][j][r];
                if constexpr (EPI == 0) {
                    short* Yb = (short*)Y + (size_t)b * ybstride;
                    Yb[(size_t)gm * ldy + gn] = (short)f2bf(v + bias[gn]);
                } else if constexpr (EPI == 1) {
                    if (gm < mlim && gn < nlim) {
                        float* Yb = (float*)Y + (size_t)b * ybstride;
                        Yb[(size_t)gm * ldy + gn] = v;
                    }
                } else {
                    if (gn < nlim) {
                        float* Yb = (float*)Y + (size_t)b * ybstride;
                        float o = (v + bias[gm]) * S[b * LPIX + gn]
                                + PT[((size_t)b * CCH + gm) * LPIX + gn];
                        Yb[(size_t)gm * ldy + gn] = o;
                    }
                }
            }
        }
    }
}

// ---------------- per-pixel squared channel norms (bf16 inputs) ----------------
__global__ __launch_bounds__(256) void sqnorm_k(
    const short* __restrict__ qt, const short* __restrict__ kt,
    float* __restrict__ nq, float* __restrict__ nk)
{
    const int b = blockIdx.y;
    const int l = blockIdx.x * 4 + threadIdx.y;
    const int lane = threadIdx.x;
    const int z = blockIdx.z;
    const short* src = z ? (kt + ((size_t)b * LPAD + l) * CCH)
                         : (qt + ((size_t)b * LPAD + l) * 4096);
    float s = 0.f;
    #pragma unroll
    for (int j = 0; j < 8; ++j) {
        u16x4 u = *(const u16x4*)(src + (lane + j * 64) * 4);
        float a = bf2f(u.x), c = bf2f(u.y), d = bf2f(u.z), e = bf2f(u.w);
        s += a * a + c * c + d * d + e * e;
    }
    #pragma unroll
    for (int off = 32; off > 0; off >>= 1)
        s += __shfl_down(s, off);
    if (lane == 0) (z ? nk : nq)[b * LPIX + l] = s;
}

// ---------------- 3x3 box filter + inverse sqrt of patch norms ----------------
__global__ void boxinv_k(const float* __restrict__ nk, const float* __restrict__ nq,
                         float* __restrict__ invNk, float* __restrict__ invNq)
{
    int idx = blockIdx.x * 256 + threadIdx.x;
    if (idx >= 2 * NB * LPIX) return;
    int map = idx / (NB * LPIX);
    int rem = idx % (NB * LPIX);
    int b = rem / LPIX, l = rem % LPIX;
    int i = l / 24, j = l % 24;
    const float* src = map ? nq : nk;
    float s = 0.f;
    for (int di = -1; di <= 1; ++di)
        for (int dj = -1; dj <= 1; ++dj) {
            int ii = i + di, jj = j + dj;
            if (ii >= 0 && ii < 24 && jj >= 0 && jj < 24)
                s += src[b * LPIX + ii * 24 + jj];
        }
    float n = fmaxf(sqrtf(s), 1e-12f);
    (map ? invNq : invNk)[b * LPIX + l] = 1.0f / n;
}

// ---------------- fused dj+di 9-tap aggregation + normalized argmax ----------------
__global__ __launch_bounds__(256) void argmax_k(
    const float* __restrict__ M,
    const float* __restrict__ invNk, const float* __restrict__ invNq,
    float* __restrict__ S, int* __restrict__ Arg)
{
    const int b = blockIdx.y;
    const int tx = threadIdx.x, ty = threadIdx.y;
    const int lt = blockIdx.x * 64 + tx;
    const int it = lt / 24, jt = lt % 24;
    const float* Mb = M + (size_t)b * LPIX * LPIX;
    float best = -1e30f; int bidx = 0;
    for (int lr = ty; lr < LPIX; lr += 4) {
        int ir = lr / 24, jr = lr % 24;
        float g = 0.f;
        #pragma unroll
        for (int di = -1; di <= 1; ++di) {
            if (ir + di < 0 || ir + di > 23 || it + di < 0 || it + di > 23) continue;
            #pragma unroll
            for (int dj = -1; dj <= 1; ++dj) {
                if (jr + dj < 0 || jr + dj > 23 || jt + dj < 0 || jt + dj > 23) continue;
                int s = di * 24 + dj;
                g += Mb[(size_t)(lr + s) * LPIX + lt + s];
            }
        }
        float v = g * invNk[b * LPIX + lr];
        if (v > best) { best = v; bidx = lr; }
    }
    __shared__ float rv[4][64];
    __shared__ int   ri[4][64];
    rv[ty][tx] = best; ri[ty][tx] = bidx;
    __syncthreads();
    if (ty == 0) {
        for (int y = 1; y < 4; ++y) {
            float v = rv[y][tx]; int id = ri[y][tx];
            if (v > best || (v == best && id < bidx)) { best = v; bidx = id; }
        }
        S[b * LPIX + lt]   = best * invNq[b * LPIX + lt];
        Arg[b * LPIX + lt] = bidx;
    }
}

// ---------------- gather best ref patches + fold (overlap-add /9) -> x2t[:,2048:] bf16 ----
__global__ __launch_bounds__(256) void gather_k(
    const short* __restrict__ kt, const int* __restrict__ Arg,
    short* __restrict__ x2t)
{
    const int b = blockIdx.y;
    const int l0 = blockIdx.x * 4;
    const int lane = threadIdx.x, ty = threadIdx.y;
    const int tid = ty * 64 + lane;
    __shared__ int tap[4][9];
    if (tid < 36) {
        int px = tid / 9, t9 = tid % 9;
        int l = l0 + px;
        int i = l / 24, j = l % 24;
        int ki = t9 / 3, kj = t9 % 3;
        int ip = i + 1 - ki, jp = j + 1 - kj;
        int off = -1;
        if (ip >= 0 && ip < 24 && jp >= 0 && jp < 24) {
            int a = Arg[b * LPIX + ip * 24 + jp];
            int rr = a / 24 + ki - 1;
            int cc = a % 24 + kj - 1;
            if (rr >= 0 && rr < 24 && cc >= 0 && cc < 24) off = rr * 24 + cc;
        }
        tap[px][t9] = off;
    }
    __syncthreads();
    const int l = l0 + ty;
    const short* Kb = kt + (size_t)b * LPAD * CCH;
    short* dst = x2t + ((size_t)b * LPAD + l) * 4096 + CCH;
    int t[9];
    #pragma unroll
    for (int i = 0; i < 9; ++i) t[i] = tap[ty][i];
    const float inv9 = 1.0f / 9.0f;
    #pragma unroll
    for (int j = 0; j < 8; ++j) {
        int c = (lane + j * 64) * 4;
        float s0 = 0.f, s1 = 0.f, s2 = 0.f, s3 = 0.f;
        #pragma unroll
        for (int t9 = 0; t9 < 9; ++t9) {
            int off = t[t9];
            if (off < 0) continue;
            u16x4 u = *(const u16x4*)(Kb + (size_t)off * CCH + c);
            s0 += bf2f(u.x); s1 += bf2f(u.y); s2 += bf2f(u.z); s3 += bf2f(u.w);
        }
        u16x4 o;
        o.x = f2bf(s0 * inv9); o.y = f2bf(s1 * inv9);
        o.z = f2bf(s2 * inv9); o.w = f2bf(s3 * inv9);
        *(u16x4*)(dst + c) = o;
    }
}

extern "C" void kernel_launch(void* const* d_in, const int* in_sizes, int n_in,
                              void* d_out, int out_size, void* d_ws, size_t ws_size,
                              hipStream_t stream) {
    const float* part_ref = (const float*)d_in[0];
    const float* part_tgt = (const float*)d_in[1];
    const float* wq = (const float*)d_in[2];
    const float* bq = (const float*)d_in[3];
    const float* wk = (const float*)d_in[4];
    const float* bk = (const float*)d_in[5];
    const float* wt = (const float*)d_in[6];
    const float* bt = (const float*)d_in[7];
    float* out = (float*)d_out;

    // ws layout (shorts): wqb|wkb (later reused as wtb) | T1 (later Mbuf) | kt | x2t | small fp32
    short* wqb = (short*)d_ws;
    short* wkb = wqb + (size_t)CCH * CCH;
    short* wtb = wqb;                                  // reuses wqb+wkb after convs
    short* T1  = wkb + (size_t)CCH * CCH;
    short* kt  = T1 + (size_t)NB * LPAD * CCH;
    short* x2t = kt + (size_t)NB * LPAD * CCH;
    float* Mbuf = (float*)T1;                          // aliases T1 (dead by gram time)
    float* nk   = (float*)(x2t + (size_t)NB * LPAD * 4096);
    float* nq    = nk + NB * LPIX;
    float* invNk = nq + NB * LPIX;
    float* invNq = invNk + NB * LPIX;
    float* Sbuf  = invNq + NB * LPIX;
    int*   Arg   = (int*)(Sbuf + NB * LPIX);

    wcast_k<<<4096, 256, 0, stream>>>(wq, wqb, CCH * CCH);
    wcast_k<<<4096, 256, 0, stream>>>(wk, wkb, CCH * CCH);

    // q = (tgt^T W_q^T + b_q) -> x2t[:, :, 0:2048] bf16  (layout [b][l][o])
    tcast_k<<<dim3(20, 64, NB), dim3(32, 8), 0, stream>>>(part_tgt, T1);
    mmbt_k<0><<<dim3(16, 5, NB), 256, 0, stream>>>(
        T1, CCH, (size_t)LPAD * CCH, wqb, CCH, 0, CCH,
        x2t, 4096, (size_t)LPAD * 4096, LPAD, CCH, bq, nullptr, nullptr);

    // k -> kt [b][l][o] bf16
    tcast_k<<<dim3(20, 64, NB), dim3(32, 8), 0, stream>>>(part_ref, T1);
    mmbt_k<0><<<dim3(16, 5, NB), 256, 0, stream>>>(
        T1, CCH, (size_t)LPAD * CCH, wkb, CCH, 0, CCH,
        kt, CCH, (size_t)LPAD * CCH, LPAD, CCH, bk, nullptr, nullptr);

    // per-pixel squared norms -> 3x3 box -> 1/norm
    sqnorm_k<<<dim3(144, NB, 2), dim3(64, 4), 0, stream>>>(x2t, kt, nq, nk);
    boxinv_k<<<18, 256, 0, stream>>>(nk, nq, invNk, invNq);

    // gram M[lr][lt] = sum_c k[lr][c] q[lt][c]
    mmbt_k<1><<<dim3(5, 5, NB), 256, 0, stream>>>(
        kt, CCH, (size_t)LPAD * CCH, x2t, 4096, (size_t)LPAD * 4096, CCH,
        Mbuf, LPIX, (size_t)LPIX * LPIX, LPIX, LPIX, nullptr, nullptr, nullptr);

    // fused 9-tap + argmax
    argmax_k<<<dim3(9, NB), dim3(64, 4), 0, stream>>>(Mbuf, invNk, invNq, Sbuf, Arg);

    // gather/fold -> x2t[:, :, 2048:4096]
    gather_k<<<dim3(144, NB), dim3(64, 4), 0, stream>>>(kt, Arg, x2t);

    // wt cast (reuses wqb|wkb region), then final fused conv
    wcast_k<<<8192, 256, 0, stream>>>(wt, wtb, CCH * 4096);
    mmbt_k<2><<<dim3(5, 16, NB), 256, 0, stream>>>(
        wtb, 4096, 0, x2t, 4096, (size_t)LPAD * 4096, 4096,
        out, LPIX, (size_t)CCH * LPIX, CCH, LPIX, bt, Sbuf, part_tgt);
}

// Round 3
// 481.342 us; speedup vs baseline: 3.6760x; 1.4541x over previous
//
#include <hip/hip_runtime.h>
#include <cstddef>
#include <cstdint>

#define LPIX 576
#define LPAD 640
#define CCH  2048
#define NB   4

typedef __attribute__((ext_vector_type(8))) short short8;
typedef __attribute__((ext_vector_type(4))) float f32x4;
typedef __attribute__((ext_vector_type(4))) unsigned short u16x4;

__device__ __forceinline__ unsigned short f2bf(float f) {
    uint32_t u = __builtin_bit_cast(uint32_t, f);
    u += 0x7fff + ((u >> 16) & 1);          // round-to-nearest-even
    return (unsigned short)(u >> 16);
}
__device__ __forceinline__ float bf2f(unsigned short s) {
    return __builtin_bit_cast(float, (uint32_t)s << 16);
}

__device__ __forceinline__ void gload_lds16(const void* g, void* l) {
    __builtin_amdgcn_global_load_lds((const __attribute__((address_space(1))) void*)g,
                                     (__attribute__((address_space(3))) void*)l, 16, 0, 0);
}

// ---------------- weight cast fp32 -> bf16 (same layout) ----------------
__global__ __launch_bounds__(256) void wcast_k(const float* __restrict__ W,
                                               short* __restrict__ Wb, int n) {
    int i = (blockIdx.x * 256 + threadIdx.x) * 4;
    if (i >= n) return;
    float4 v = *(const float4*)(W + i);
    u16x4 u;
    u.x = f2bf(v.x); u.y = f2bf(v.y); u.z = f2bf(v.z); u.w = f2bf(v.w);
    *(u16x4*)(Wb + i) = u;
}

// ---------------- transpose-cast: X[b][c][l] fp32 -> T[b][l][c] bf16, l padded to 640 ----
__global__ __launch_bounds__(256) void tcast_k(const float* __restrict__ X,
                                               short* __restrict__ T) {
    __shared__ float tile[32][33];
    const int b = blockIdx.z;
    const int c0 = blockIdx.y * 32;
    const int l0 = blockIdx.x * 32;
    const int tx = threadIdx.x, ty = threadIdx.y;
    #pragma unroll
    for (int j = 0; j < 4; ++j) {
        int c = c0 + ty + j * 8;
        int l = l0 + tx;
        float v = 0.f;
        if (l < LPIX) v = X[((size_t)b * CCH + c) * LPIX + l];
        tile[ty + j * 8][tx] = v;
    }
    __syncthreads();
    #pragma unroll
    for (int j = 0; j < 4; ++j) {
        int l = l0 + ty + j * 8;
        int c = c0 + tx;
        T[((size_t)b * LPAD + l) * CCH + c] = (short)f2bf(tile[tx][ty + j * 8]);
    }
}

// ---------------- MFMA GEMM: D[m][n] = sum_k A[m][k]*B[n][k]  (both k-contiguous bf16) ----
// EPI 0: conv  -> bf16 out, += bias[n], no mask
// EPI 1: gram  -> fp32 out, mask m<mlim && n<nlim
// EPI 2: final -> fp32 out, += bias[m], *S[n], += PT[m][n], mask n<nlim
template<int EPI>
__global__ __launch_bounds__(256) void mmbt_k(
    const short* __restrict__ A, int lda, size_t abstride,
    const short* __restrict__ B, int ldb, size_t bbstride,
    int K,
    void* __restrict__ Y, int ldy, size_t ybstride, int mlim, int nlim,
    const float* __restrict__ bias,
    const float* __restrict__ S, const float* __restrict__ PT)
{
    __shared__ short As[128 * 32];
    __shared__ short Bs[128 * 32];
    const int b  = blockIdx.z;
    const int m0 = blockIdx.y * 128;
    const int n0 = blockIdx.x * 128;
    const short* Ab = A + (size_t)b * abstride;
    const short* Bb = B + (size_t)b * bbstride;
    const int tid  = threadIdx.x;
    const int lane = tid & 63;
    const int w    = tid >> 6;
    const int r1 = tid >> 2;
    const int k1 = (tid & 3) * 8;
    const int wm = (w & 1) * 64;
    const int wn = (w >> 1) * 64;
    const int l15 = lane & 15;
    const int quad = lane >> 4;
    const int k8 = quad * 8;

    f32x4 acc[4][4] = {};

    const short* Asrc1 = Ab + (size_t)(m0 + r1) * lda + k1;
    const short* Asrc2 = Ab + (size_t)(m0 + r1 + 64) * lda + k1;
    const short* Bsrc1 = Bb + (size_t)(n0 + r1) * ldb + k1;
    const short* Bsrc2 = Bb + (size_t)(n0 + r1 + 64) * ldb + k1;
    short* ldsA1 = As + tid * 8;
    short* ldsA2 = As + (tid + 256) * 8;
    short* ldsB1 = Bs + tid * 8;
    short* ldsB2 = Bs + (tid + 256) * 8;

    for (int c0 = 0; c0 < K; c0 += 32) {
        gload_lds16(Asrc1 + c0, ldsA1);
        gload_lds16(Asrc2 + c0, ldsA2);
        gload_lds16(Bsrc1 + c0, ldsB1);
        gload_lds16(Bsrc2 + c0, ldsB2);
        __syncthreads();
        short8 fa[4], fb[4];
        #pragma unroll
        for (int i = 0; i < 4; ++i)
            fa[i] = *(const short8*)(As + (wm + i * 16 + l15) * 32 + k8);
        #pragma unroll
        for (int i = 0; i < 4; ++i)
            fb[i] = *(const short8*)(Bs + (wn + i * 16 + l15) * 32 + k8);
        #pragma unroll
        for (int i = 0; i < 4; ++i)
            #pragma unroll
            for (int j = 0; j < 4; ++j)
                acc[i][j] = __builtin_amdgcn_mfma_f32_16x16x32_bf16(fa[i], fb[j], acc[i][j], 0, 0, 0);
        __syncthreads();
    }

    #pragma unroll
    for (int i = 0; i < 4; ++i) {
        #pragma unroll
        for (int j = 0; j < 4; ++j) {
            const int gn = n0 + wn + j * 16 + l15;
            #pragma unroll
            for (int r = 0; r < 4; ++r) {
                const int gm = m0 + wm + i * 16 + quad * 4 + r;
                float v = acc[i][j][r];
                if constexpr (EPI == 0) {
                    short* Yb = (short*)Y + (size_t)b * ybstride;
                    Yb[(size_t)gm * ldy + gn] = (short)f2bf(v + bias[gn]);
                } else if constexpr (EPI == 1) {
                    if (gm < mlim && gn < nlim) {
                        float* Yb = (float*)Y + (size_t)b * ybstride;
                        Yb[(size_t)gm * ldy + gn] = v;
                    }
                } else {
                    if (gn < nlim) {
                        float* Yb = (float*)Y + (size_t)b * ybstride;
                        float o = (v + bias[gm]) * S[b * LPIX + gn]
                                + PT[((size_t)b * CCH + gm) * LPIX + gn];
                        Yb[(size_t)gm * ldy + gn] = o;
                    }
                }
            }
        }
    }
}

// ---------------- per-pixel squared channel norms (bf16 inputs) ----------------
__global__ __launch_bounds__(256) void sqnorm_k(
    const short* __restrict__ qt, const short* __restrict__ kt,
    float* __restrict__ nq, float* __restrict__ nk)
{
    const int b = blockIdx.y;
    const int l = blockIdx.x * 4 + threadIdx.y;
    const int lane = threadIdx.x;
    const int z = blockIdx.z;
    const short* src = z ? (kt + ((size_t)b * LPAD + l) * CCH)
                         : (qt + ((size_t)b * LPAD + l) * 4096);
    float s = 0.f;
    #pragma unroll
    for (int j = 0; j < 8; ++j) {
        u16x4 u = *(const u16x4*)(src + (lane + j * 64) * 4);
        float a = bf2f(u.x), c = bf2f(u.y), d = bf2f(u.z), e = bf2f(u.w);
        s += a * a + c * c + d * d + e * e;
    }
    #pragma unroll
    for (int off = 32; off > 0; off >>= 1)
        s += __shfl_down(s, off);
    if (lane == 0) (z ? nk : nq)[b * LPIX + l] = s;
}

// ---------------- 3x3 box filter + inverse sqrt of patch norms ----------------
__global__ void boxinv_k(const float* __restrict__ nk, const float* __restrict__ nq,
                         float* __restrict__ invNk, float* __restrict__ invNq)
{
    int idx = blockIdx.x * 256 + threadIdx.x;
    if (idx >= 2 * NB * LPIX) return;
    int map = idx / (NB * LPIX);
    int rem = idx % (NB * LPIX);
    int b = rem / LPIX, l = rem % LPIX;
    int i = l / 24, j = l % 24;
    const float* src = map ? nq : nk;
    float s = 0.f;
    for (int di = -1; di <= 1; ++di)
        for (int dj = -1; dj <= 1; ++dj) {
            int ii = i + di, jj = j + dj;
            if (ii >= 0 && ii < 24 && jj >= 0 && jj < 24)
                s += src[b * LPIX + ii * 24 + jj];
        }
    float n = fmaxf(sqrtf(s), 1e-12f);
    (map ? invNq : invNk)[b * LPIX + l] = 1.0f / n;
}

// ---------------- stage 1: 9-tap aggregation + partial argmax over a 24-row lr chunk ----
__global__ __launch_bounds__(256) void argmax1_k(
    const float* __restrict__ M, const float* __restrict__ invNk,
    float* __restrict__ Pv, int* __restrict__ Pi)
{
    const int b   = blockIdx.z;
    const int lrb = blockIdx.y;                 // 0..23, chunk of 24 lr rows
    const int tx = threadIdx.x, ty = threadIdx.y;
    const int lt = blockIdx.x * 64 + tx;
    const int it = lt / 24, jt = lt % 24;
    const float* Mb = M + (size_t)b * LPIX * LPIX;
    float best = -1e30f; int bidx = 0;
    #pragma unroll
    for (int i = 0; i < 6; ++i) {
        const int lr = lrb * 24 + ty + i * 4;
        const int ir = lr / 24, jr = lr % 24;
        const int base = lr * LPIX + lt;
        float g = 0.f;
        #pragma unroll
        for (int di = -1; di <= 1; ++di) {
            if ((unsigned)(ir + di) > 23u || (unsigned)(it + di) > 23u) continue;
            #pragma unroll
            for (int dj = -1; dj <= 1; ++dj) {
                if ((unsigned)(jr + dj) > 23u || (unsigned)(jt + dj) > 23u) continue;
                g += Mb[base + (di * 24 + dj) * (LPIX + 1)];
            }
        }
        float v = g * invNk[b * LPIX + lr];
        if (v > best) { best = v; bidx = lr; }
    }
    __shared__ float rv[4][64];
    __shared__ int   ri[4][64];
    rv[ty][tx] = best; ri[ty][tx] = bidx;
    __syncthreads();
    if (ty == 0) {
        #pragma unroll
        for (int y = 1; y < 4; ++y) {
            float v = rv[y][tx]; int id = ri[y][tx];
            if (v > best || (v == best && id < bidx)) { best = v; bidx = id; }
        }
        Pv[((size_t)b * 24 + lrb) * LPIX + lt] = best;
        Pi[((size_t)b * 24 + lrb) * LPIX + lt] = bidx;
    }
}

// ---------------- stage 2: fold 24 partials (ascending lr order -> first-max ties) ----
__global__ __launch_bounds__(256) void argmax2_k(
    const float* __restrict__ Pv, const int* __restrict__ Pi,
    const float* __restrict__ invNq,
    float* __restrict__ S, int* __restrict__ Arg)
{
    int idx = blockIdx.x * 256 + threadIdx.x;
    if (idx >= NB * LPIX) return;
    int b = idx / LPIX, lt = idx % LPIX;
    float best = -1e30f; int bidx = 0;
    #pragma unroll
    for (int c = 0; c < 24; ++c) {
        float v = Pv[((size_t)b * 24 + c) * LPIX + lt];
        int  id = Pi[((size_t)b * 24 + c) * LPIX + lt];
        if (v > best || (v == best && id < bidx)) { best = v; bidx = id; }
    }
    S[idx]   = best * invNq[idx];
    Arg[idx] = bidx;
}

// ---------------- gather best ref patches + fold (overlap-add /9) -> x2t[:,2048:] bf16 ----
__global__ __launch_bounds__(256) void gather_k(
    const short* __restrict__ kt, const int* __restrict__ Arg,
    short* __restrict__ x2t)
{
    const int b = blockIdx.y;
    const int l0 = blockIdx.x * 4;
    const int lane = threadIdx.x, ty = threadIdx.y;
    const int tid = ty * 64 + lane;
    __shared__ int tap[4][9];
    if (tid < 36) {
        int px = tid / 9, t9 = tid % 9;
        int l = l0 + px;
        int i = l / 24, j = l % 24;
        int ki = t9 / 3, kj = t9 % 3;
        int ip = i + 1 - ki, jp = j + 1 - kj;
        int off = -1;
        if (ip >= 0 && ip < 24 && jp >= 0 && jp < 24) {
            int a = Arg[b * LPIX + ip * 24 + jp];
            int rr = a / 24 + ki - 1;
            int cc = a % 24 + kj - 1;
            if (rr >= 0 && rr < 24 && cc >= 0 && cc < 24) off = rr * 24 + cc;
        }
        tap[px][t9] = off;
    }
    __syncthreads();
    const int l = l0 + ty;
    const short* Kb = kt + (size_t)b * LPAD * CCH;
    short* dst = x2t + ((size_t)b * LPAD + l) * 4096 + CCH;
    int t[9];
    #pragma unroll
    for (int i = 0; i < 9; ++i) t[i] = tap[ty][i];
    const float inv9 = 1.0f / 9.0f;
    #pragma unroll
    for (int j = 0; j < 8; ++j) {
        int c = (lane + j * 64) * 4;
        float s0 = 0.f, s1 = 0.f, s2 = 0.f, s3 = 0.f;
        #pragma unroll
        for (int t9 = 0; t9 < 9; ++t9) {
            int off = t[t9];
            if (off < 0) continue;
            u16x4 u = *(const u16x4*)(Kb + (size_t)off * CCH + c);
            s0 += bf2f(u.x); s1 += bf2f(u.y); s2 += bf2f(u.z); s3 += bf2f(u.w);
        }
        u16x4 o;
        o.x = f2bf(s0 * inv9); o.y = f2bf(s1 * inv9);
        o.z = f2bf(s2 * inv9); o.w = f2bf(s3 * inv9);
        *(u16x4*)(dst + c) = o;
    }
}

extern "C" void kernel_launch(void* const* d_in, const int* in_sizes, int n_in,
                              void* d_out, int out_size, void* d_ws, size_t ws_size,
                              hipStream_t stream) {
    const float* part_ref = (const float*)d_in[0];
    const float* part_tgt = (const float*)d_in[1];
    const float* wq = (const float*)d_in[2];
    const float* bq = (const float*)d_in[3];
    const float* wk = (const float*)d_in[4];
    const float* bk = (const float*)d_in[5];
    const float* wt = (const float*)d_in[6];
    const float* bt = (const float*)d_in[7];
    float* out = (float*)d_out;

    short* wqb = (short*)d_ws;
    short* wkb = wqb + (size_t)CCH * CCH;
    short* wtb = wqb;                                  // reuses wqb+wkb after convs
    short* T1  = wkb + (size_t)CCH * CCH;
    short* kt  = T1 + (size_t)NB * LPAD * CCH;
    short* x2t = kt + (size_t)NB * LPAD * CCH;
    float* Mbuf = (float*)T1;                          // aliases T1 (dead by gram time)
    float* nk   = (float*)(x2t + (size_t)NB * LPAD * 4096);
    float* nq    = nk + NB * LPIX;
    float* invNk = nq + NB * LPIX;
    float* invNq = invNk + NB * LPIX;
    float* Sbuf  = invNq + NB * LPIX;
    int*   Arg   = (int*)(Sbuf + NB * LPIX);
    float* Pv    = (float*)(Arg + NB * LPIX);          // 24*NB*LPIX
    int*   Pi    = (int*)(Pv + (size_t)24 * NB * LPIX);

    wcast_k<<<4096, 256, 0, stream>>>(wq, wqb, CCH * CCH);
    wcast_k<<<4096, 256, 0, stream>>>(wk, wkb, CCH * CCH);

    // q -> x2t[:, :, 0:2048] bf16  (layout [b][l][o])
    tcast_k<<<dim3(20, 64, NB), dim3(32, 8), 0, stream>>>(part_tgt, T1);
    mmbt_k<0><<<dim3(16, 5, NB), 256, 0, stream>>>(
        T1, CCH, (size_t)LPAD * CCH, wqb, CCH, 0, CCH,
        x2t, 4096, (size_t)LPAD * 4096, LPAD, CCH, bq, nullptr, nullptr);

    // k -> kt [b][l][o] bf16
    tcast_k<<<dim3(20, 64, NB), dim3(32, 8), 0, stream>>>(part_ref, T1);
    mmbt_k<0><<<dim3(16, 5, NB), 256, 0, stream>>>(
        T1, CCH, (size_t)LPAD * CCH, wkb, CCH, 0, CCH,
        kt, CCH, (size_t)LPAD * CCH, LPAD, CCH, bk, nullptr, nullptr);

    sqnorm_k<<<dim3(144, NB, 2), dim3(64, 4), 0, stream>>>(x2t, kt, nq, nk);
    boxinv_k<<<18, 256, 0, stream>>>(nk, nq, invNk, invNq);

    // gram M[lr][lt] = sum_c k[lr][c] q[lt][c]
    mmbt_k<1><<<dim3(5, 5, NB), 256, 0, stream>>>(
        kt, CCH, (size_t)LPAD * CCH, x2t, 4096, (size_t)LPAD * 4096, CCH,
        Mbuf, LPIX, (size_t)LPIX * LPIX, LPIX, LPIX, nullptr, nullptr, nullptr);

    // two-stage 9-tap + argmax
    argmax1_k<<<dim3(9, 24, NB), dim3(64, 4), 0, stream>>>(Mbuf, invNk, Pv, Pi);
    argmax2_k<<<9, 256, 0, stream>>>(Pv, Pi, invNq, Sbuf, Arg);

    // gather/fold -> x2t[:, :, 2048:4096]
    gather_k<<<dim3(144, NB), dim3(64, 4), 0, stream>>>(kt, Arg, x2t);

    // wt cast (reuses wqb|wkb region), then final fused conv
    wcast_k<<<8192, 256, 0, stream>>>(wt, wtb, CCH * 4096);
    mmbt_k<2><<<dim3(5, 16, NB), 256, 0, stream>>>(
        wtb, 4096, 0, x2t, 4096, (size_t)LPAD * 4096, 4096,
        out, LPIX, (size_t)CCH * LPIX, CCH, LPIX, bt, Sbuf, part_tgt);
}

// Round 4
// 385.850 us; speedup vs baseline: 4.5857x; 1.2475x over previous
//
#include <hip/hip_runtime.h>
#include <cstddef>
#include <cstdint>

#define LPIX 576
#define CCH  2048
#define NB   4

typedef __attribute__((ext_vector_type(8))) short short8;
typedef __attribute__((ext_vector_type(4))) float f32x4;
typedef __attribute__((ext_vector_type(4))) unsigned short u16x4;

__device__ __forceinline__ unsigned short f2bf(float f) {
    uint32_t u = __builtin_bit_cast(uint32_t, f);
    u += 0x7fff + ((u >> 16) & 1);          // round-to-nearest-even
    return (unsigned short)(u >> 16);
}
__device__ __forceinline__ float bf2f(unsigned short s) {
    return __builtin_bit_cast(float, (uint32_t)s << 16);
}

__device__ __forceinline__ void gload_lds16(const void* g, void* l) {
    __builtin_amdgcn_global_load_lds((const __attribute__((address_space(1))) void*)g,
                                     (__attribute__((address_space(3))) void*)l, 16, 0, 0);
}

// ---------------- shared MFMA K-loop: D[m][n] += A[m][k]*B[n][k], bf16, k-contiguous ----
// BM,BN in {64,128}. 256 threads = 4 waves arranged 2x2 over the tile.
template<int BM, int BN>
__device__ __forceinline__ void mm_core(
    const short* __restrict__ Ab, int lda,
    const short* __restrict__ Bb, int ldb,
    int k0, int kend, short* As, short* Bs,
    int m0, int n0, f32x4 (&acc)[BM/32][BN/32])
{
    const int tid  = threadIdx.x;
    const int lane = tid & 63;
    const int w    = tid >> 6;
    const int wm = (w & 1) * (BM / 2);
    const int wn = (w >> 1) * (BN / 2);
    const int l15 = lane & 15;
    const int k8  = (lane >> 4) * 8;
    const int r   = tid >> 2;
    const int kk  = (tid & 3) * 8;

    const short* Aptr[BM / 64];
    const short* Bptr[BN / 64];
    #pragma unroll
    for (int u = 0; u < BM / 64; ++u) Aptr[u] = Ab + (size_t)(m0 + r + u * 64) * lda + kk;
    #pragma unroll
    for (int u = 0; u < BN / 64; ++u) Bptr[u] = Bb + (size_t)(n0 + r + u * 64) * ldb + kk;

    for (int c0 = k0; c0 < kend; c0 += 32) {
        #pragma unroll
        for (int u = 0; u < BM / 64; ++u)
            gload_lds16(Aptr[u] + c0, As + (tid + u * 256) * 8);
        #pragma unroll
        for (int u = 0; u < BN / 64; ++u)
            gload_lds16(Bptr[u] + c0, Bs + (tid + u * 256) * 8);
        __syncthreads();
        short8 fa[BM / 32], fb[BN / 32];
        #pragma unroll
        for (int i = 0; i < BM / 32; ++i)
            fa[i] = *(const short8*)(As + (wm + i * 16 + l15) * 32 + k8);
        #pragma unroll
        for (int j = 0; j < BN / 32; ++j)
            fb[j] = *(const short8*)(Bs + (wn + j * 16 + l15) * 32 + k8);
        #pragma unroll
        for (int i = 0; i < BM / 32; ++i)
            #pragma unroll
            for (int j = 0; j < BN / 32; ++j)
                acc[i][j] = __builtin_amdgcn_mfma_f32_16x16x32_bf16(fa[i], fb[j], acc[i][j], 0, 0, 0);
        __syncthreads();
    }
}

// ---------------- both weight casts in one dispatch ----------------
__global__ __launch_bounds__(256) void wcast2_k(const float* __restrict__ wq,
                                                const float* __restrict__ wk,
                                                short* __restrict__ Wb) {
    const float* W = blockIdx.y ? wk : wq;
    short* D = Wb + (size_t)blockIdx.y * CCH * CCH;
    int i = (blockIdx.x * 256 + threadIdx.x) * 4;
    float4 v = *(const float4*)(W + i);
    u16x4 u;
    u.x = f2bf(v.x); u.y = f2bf(v.y); u.z = f2bf(v.z); u.w = f2bf(v.w);
    *(u16x4*)(D + i) = u;
}

__global__ __launch_bounds__(256) void wcast_k(const float* __restrict__ W,
                                               short* __restrict__ Wb) {
    int i = (blockIdx.x * 256 + threadIdx.x) * 4;
    float4 v = *(const float4*)(W + i);
    u16x4 u;
    u.x = f2bf(v.x); u.y = f2bf(v.y); u.z = f2bf(v.z); u.w = f2bf(v.w);
    *(u16x4*)(Wb + i) = u;
}

// ---------------- merged transpose-cast: tgt & ref [b][c][l] fp32 -> T1[which][b][l][c] bf16 ----
__global__ __launch_bounds__(256) void tcast_k(const float* __restrict__ tgt,
                                               const float* __restrict__ ref,
                                               short* __restrict__ T1) {
    __shared__ float tile[32][33];
    const int z = blockIdx.z;
    const int b = z & 3, which = z >> 2;
    const float* X = (which ? ref : tgt) + (size_t)b * CCH * LPIX;
    const int c0 = blockIdx.y * 32;
    const int l0 = blockIdx.x * 32;
    const int tx = threadIdx.x, ty = threadIdx.y;
    #pragma unroll
    for (int j = 0; j < 4; ++j)
        tile[ty + j * 8][tx] = X[(size_t)(c0 + ty + j * 8) * LPIX + l0 + tx];
    __syncthreads();
    short* D = T1 + ((size_t)(which * NB + b) * LPIX) * CCH;
    #pragma unroll
    for (int j = 0; j < 4; ++j)
        D[(size_t)(l0 + ty + j * 8) * CCH + c0 + tx] = (short)f2bf(tile[tx][ty + j * 8]);
}

// ---------------- merged q/k conv: 64(l) x 128(o) tiles, z = b*2+which ----------------
__global__ __launch_bounds__(256) void conv_k(
    const short* __restrict__ T1, const short* __restrict__ Wb,
    const float* __restrict__ bq, const float* __restrict__ bk,
    short* __restrict__ x2t, short* __restrict__ kt)
{
    __shared__ short As[64 * 32];
    __shared__ short Bs[128 * 32];
    const int z = blockIdx.z;
    const int b = z >> 1, which = z & 1;
    const short* Ab = T1 + (size_t)(which * NB + b) * LPIX * CCH;
    const short* Bb = Wb + (size_t)which * CCH * CCH;
    const float* bias = which ? bk : bq;
    short* Yb = which ? (kt + (size_t)b * LPIX * CCH) : (x2t + (size_t)b * LPIX * 4096);
    const int ldy = which ? CCH : 4096;
    const int m0 = blockIdx.y * 64;    // l
    const int n0 = blockIdx.x * 128;   // o
    f32x4 acc[2][4] = {};
    mm_core<64, 128>(Ab, CCH, Bb, CCH, 0, CCH, As, Bs, m0, n0, acc);
    const int lane = threadIdx.x & 63, w = threadIdx.x >> 6;
    const int wm = (w & 1) * 32, wn = (w >> 1) * 64;
    const int l15 = lane & 15, quad = lane >> 4;
    #pragma unroll
    for (int i = 0; i < 2; ++i)
        #pragma unroll
        for (int j = 0; j < 4; ++j) {
            const int gn = n0 + wn + j * 16 + l15;
            const float bi = bias[gn];
            #pragma unroll
            for (int r = 0; r < 4; ++r) {
                const int gm = m0 + wm + i * 16 + quad * 4 + r;
                Yb[(size_t)gm * ldy + gn] = (short)f2bf(acc[i][j][r] + bi);
            }
        }
}

// ---------------- gram with split-K2: M_part[kc][b][lr][lt], 64x64 tiles ----------------
__global__ __launch_bounds__(256) void gram_k(
    const short* __restrict__ kt, const short* __restrict__ x2t,
    float* __restrict__ Mpart)
{
    __shared__ short As[64 * 32];
    __shared__ short Bs[64 * 32];
    const int z = blockIdx.z;
    const int b = z >> 1, kc = z & 1;
    const short* Ab = kt + (size_t)b * LPIX * CCH;
    const short* Bb = x2t + (size_t)b * LPIX * 4096;
    const int m0 = blockIdx.y * 64;   // lr
    const int n0 = blockIdx.x * 64;   // lt
    f32x4 acc[2][2] = {};
    mm_core<64, 64>(Ab, CCH, Bb, 4096, kc * 1024, kc * 1024 + 1024, As, Bs, m0, n0, acc);
    float* Mb = Mpart + (size_t)(kc * NB + b) * LPIX * LPIX;
    const int lane = threadIdx.x & 63, w = threadIdx.x >> 6;
    const int wm = (w & 1) * 32, wn = (w >> 1) * 32;
    const int l15 = lane & 15, quad = lane >> 4;
    #pragma unroll
    for (int i = 0; i < 2; ++i)
        #pragma unroll
        for (int j = 0; j < 2; ++j) {
            const int gn = n0 + wn + j * 16 + l15;
            #pragma unroll
            for (int r = 0; r < 4; ++r) {
                const int gm = m0 + wm + i * 16 + quad * 4 + r;
                Mb[(size_t)gm * LPIX + gn] = acc[i][j][r];
            }
        }
}

// ---------------- final: 128(o) x 64(l), epilogue bias + *S + PT ----------------
__global__ __launch_bounds__(256) void fin_k(
    const short* __restrict__ wtb, const short* __restrict__ x2t,
    const float* __restrict__ bt, const float* __restrict__ S,
    const float* __restrict__ PT, float* __restrict__ out)
{
    __shared__ short As[128 * 32];
    __shared__ short Bs[64 * 32];
    const int b = blockIdx.z;
    const short* Bb = x2t + (size_t)b * LPIX * 4096;
    const int m0 = blockIdx.y * 128;  // o
    const int n0 = blockIdx.x * 64;   // l
    f32x4 acc[4][2] = {};
    mm_core<128, 64>(wtb, 4096, Bb, 4096, 0, 4096, As, Bs, m0, n0, acc);
    const int lane = threadIdx.x & 63, w = threadIdx.x >> 6;
    const int wm = (w & 1) * 64, wn = (w >> 1) * 32;
    const int l15 = lane & 15, quad = lane >> 4;
    #pragma unroll
    for (int i = 0; i < 4; ++i)
        #pragma unroll
        for (int j = 0; j < 2; ++j) {
            const int gn = n0 + wn + j * 16 + l15;
            const float sv = S[b * LPIX + gn];
            #pragma unroll
            for (int r = 0; r < 4; ++r) {
                const int gm = m0 + wm + i * 16 + quad * 4 + r;
                float v = (acc[i][j][r] + bt[gm]) * sv
                        + PT[((size_t)b * CCH + gm) * LPIX + gn];
                out[((size_t)b * CCH + gm) * LPIX + gn] = v;
            }
        }
}

// ---------------- per-pixel squared channel norms (bf16 inputs) ----------------
__global__ __launch_bounds__(256) void sqnorm_k(
    const short* __restrict__ qt, const short* __restrict__ kt,
    float* __restrict__ nq, float* __restrict__ nk)
{
    const int b = blockIdx.y;
    const int l = blockIdx.x * 4 + threadIdx.y;
    const int lane = threadIdx.x;
    const int z = blockIdx.z;
    const short* src = z ? (kt + ((size_t)b * LPIX + l) * CCH)
                         : (qt + ((size_t)b * LPIX + l) * 4096);
    float s = 0.f;
    #pragma unroll
    for (int j = 0; j < 8; ++j) {
        u16x4 u = *(const u16x4*)(src + (lane + j * 64) * 4);
        float a = bf2f(u.x), c = bf2f(u.y), d = bf2f(u.z), e = bf2f(u.w);
        s += a * a + c * c + d * d + e * e;
    }
    #pragma unroll
    for (int off = 32; off > 0; off >>= 1)
        s += __shfl_down(s, off);
    if (lane == 0) (z ? nk : nq)[b * LPIX + l] = s;
}

// ---------------- 3x3 box filter + inverse sqrt of patch norms ----------------
__global__ void boxinv_k(const float* __restrict__ nk, const float* __restrict__ nq,
                         float* __restrict__ invNk, float* __restrict__ invNq)
{
    int idx = blockIdx.x * 256 + threadIdx.x;
    if (idx >= 2 * NB * LPIX) return;
    int map = idx / (NB * LPIX);
    int rem = idx % (NB * LPIX);
    int b = rem / LPIX, l = rem % LPIX;
    int i = l / 24, j = l % 24;
    const float* src = map ? nq : nk;
    float s = 0.f;
    for (int di = -1; di <= 1; ++di)
        for (int dj = -1; dj <= 1; ++dj) {
            int ii = i + di, jj = j + dj;
            if (ii >= 0 && ii < 24 && jj >= 0 && jj < 24)
                s += src[b * LPIX + ii * 24 + jj];
        }
    float n = fmaxf(sqrtf(s), 1e-12f);
    (map ? invNq : invNk)[b * LPIX + l] = 1.0f / n;
}

// ---------------- stage 1: 9-tap aggregation (sum of 2 K-partials) + chunk argmax ----
__global__ __launch_bounds__(256) void argmax1_k(
    const float* __restrict__ Mpart, const float* __restrict__ invNk,
    float* __restrict__ Pv, int* __restrict__ Pi)
{
    const int b   = blockIdx.z;
    const int lrb = blockIdx.y;                 // 0..23, chunk of 24 lr rows
    const int tx = threadIdx.x, ty = threadIdx.y;
    const int lt = blockIdx.x * 64 + tx;
    const int it = lt / 24, jt = lt % 24;
    const float* Mb0 = Mpart + (size_t)b * LPIX * LPIX;
    const float* Mb1 = Mpart + (size_t)(NB + b) * LPIX * LPIX;
    float best = -1e30f; int bidx = 0;
    #pragma unroll
    for (int i = 0; i < 6; ++i) {
        const int lr = lrb * 24 + ty + i * 4;
        const int ir = lr / 24, jr = lr % 24;
        const int base = lr * LPIX + lt;
        float g = 0.f;
        #pragma unroll
        for (int di = -1; di <= 1; ++di) {
            if ((unsigned)(ir + di) > 23u || (unsigned)(it + di) > 23u) continue;
            #pragma unroll
            for (int dj = -1; dj <= 1; ++dj) {
                if ((unsigned)(jr + dj) > 23u || (unsigned)(jt + dj) > 23u) continue;
                const int o = base + (di * 24 + dj) * (LPIX + 1);
                g += Mb0[o] + Mb1[o];
            }
        }
        float v = g * invNk[b * LPIX + lr];
        if (v > best) { best = v; bidx = lr; }
    }
    __shared__ float rv[4][64];
    __shared__ int   ri[4][64];
    rv[ty][tx] = best; ri[ty][tx] = bidx;
    __syncthreads();
    if (ty == 0) {
        #pragma unroll
        for (int y = 1; y < 4; ++y) {
            float v = rv[y][tx]; int id = ri[y][tx];
            if (v > best || (v == best && id < bidx)) { best = v; bidx = id; }
        }
        Pv[((size_t)b * 24 + lrb) * LPIX + lt] = best;
        Pi[((size_t)b * 24 + lrb) * LPIX + lt] = bidx;
    }
}

// ---------------- stage 2: fold 24 partials (ascending lr -> first-max ties) ----------
__global__ __launch_bounds__(256) void argmax2_k(
    const float* __restrict__ Pv, const int* __restrict__ Pi,
    const float* __restrict__ invNq,
    float* __restrict__ S, int* __restrict__ Arg)
{
    int idx = blockIdx.x * 256 + threadIdx.x;
    if (idx >= NB * LPIX) return;
    int b = idx / LPIX, lt = idx % LPIX;
    float best = -1e30f; int bidx = 0;
    #pragma unroll
    for (int c = 0; c < 24; ++c) {
        float v = Pv[((size_t)b * 24 + c) * LPIX + lt];
        int  id = Pi[((size_t)b * 24 + c) * LPIX + lt];
        if (v > best || (v == best && id < bidx)) { best = v; bidx = id; }
    }
    S[idx]   = best * invNq[idx];
    Arg[idx] = bidx;
}

// ---------------- gather best ref patches + fold (overlap-add /9) -> x2t[:,2048:] ----
__global__ __launch_bounds__(256) void gather_k(
    const short* __restrict__ kt, const int* __restrict__ Arg,
    short* __restrict__ x2t)
{
    const int b = blockIdx.y;
    const int l0 = blockIdx.x * 4;
    const int lane = threadIdx.x, ty = threadIdx.y;
    const int tid = ty * 64 + lane;
    __shared__ int tap[4][9];
    if (tid < 36) {
        int px = tid / 9, t9 = tid % 9;
        int l = l0 + px;
        int i = l / 24, j = l % 24;
        int ki = t9 / 3, kj = t9 % 3;
        int ip = i + 1 - ki, jp = j + 1 - kj;
        int off = -1;
        if (ip >= 0 && ip < 24 && jp >= 0 && jp < 24) {
            int a = Arg[b * LPIX + ip * 24 + jp];
            int rr = a / 24 + ki - 1;
            int cc = a % 24 + kj - 1;
            if (rr >= 0 && rr < 24 && cc >= 0 && cc < 24) off = rr * 24 + cc;
        }
        tap[px][t9] = off;
    }
    __syncthreads();
    const int l = l0 + ty;
    const short* Kb = kt + (size_t)b * LPIX * CCH;
    short* dst = x2t + ((size_t)b * LPIX + l) * 4096 + CCH;
    int t[9];
    #pragma unroll
    for (int i = 0; i < 9; ++i) t[i] = tap[ty][i];
    const float inv9 = 1.0f / 9.0f;
    #pragma unroll
    for (int j = 0; j < 8; ++j) {
        int c = (lane + j * 64) * 4;
        float s0 = 0.f, s1 = 0.f, s2 = 0.f, s3 = 0.f;
        #pragma unroll
        for (int t9 = 0; t9 < 9; ++t9) {
            int off = t[t9];
            if (off < 0) continue;
            u16x4 u = *(const u16x4*)(Kb + (size_t)off * CCH + c);
            s0 += bf2f(u.x); s1 += bf2f(u.y); s2 += bf2f(u.z); s3 += bf2f(u.w);
        }
        u16x4 o;
        o.x = f2bf(s0 * inv9); o.y = f2bf(s1 * inv9);
        o.z = f2bf(s2 * inv9); o.w = f2bf(s3 * inv9);
        *(u16x4*)(dst + c) = o;
    }
}

extern "C" void kernel_launch(void* const* d_in, const int* in_sizes, int n_in,
                              void* d_out, int out_size, void* d_ws, size_t ws_size,
                              hipStream_t stream) {
    const float* part_ref = (const float*)d_in[0];
    const float* part_tgt = (const float*)d_in[1];
    const float* wq = (const float*)d_in[2];
    const float* bq = (const float*)d_in[3];
    const float* wk = (const float*)d_in[4];
    const float* bk = (const float*)d_in[5];
    const float* wt = (const float*)d_in[6];
    const float* bt = (const float*)d_in[7];
    float* out = (float*)d_out;

    // ws layout (shorts unless noted): wqb2 (2x C*C, reused as wtb) | T1 (2x NB*576*2048,
    // reused as Mpart fp32) | kt | x2t | small fp32
    short* wqb2 = (short*)d_ws;
    short* wtb  = wqb2;                                       // reuse after convs
    short* T1   = wqb2 + (size_t)2 * CCH * CCH;
    short* kt   = T1 + (size_t)2 * NB * LPIX * CCH;
    short* x2t  = kt + (size_t)NB * LPIX * CCH;
    float* Mpart = (float*)T1;                                // 2*NB*576*576 fp32 = 10.6MB <= T1 18.9MB
    float* nk    = (float*)(x2t + (size_t)NB * LPIX * 4096);
    float* nq    = nk + NB * LPIX;
    float* invNk = nq + NB * LPIX;
    float* invNq = invNk + NB * LPIX;
    float* Sbuf  = invNq + NB * LPIX;
    int*   Arg   = (int*)(Sbuf + NB * LPIX);
    float* Pv    = (float*)(Arg + NB * LPIX);                 // 24*NB*LPIX
    int*   Pi    = (int*)(Pv + (size_t)24 * NB * LPIX);

    wcast2_k<<<dim3(4096, 2), 256, 0, stream>>>(wq, wk, wqb2);
    tcast_k<<<dim3(18, 64, 8), dim3(32, 8), 0, stream>>>(part_tgt, part_ref, T1);

    // q -> x2t[:, :, 0:2048]; k -> kt   (one dispatch, 1152 blocks)
    conv_k<<<dim3(16, 9, 8), 256, 0, stream>>>(T1, wqb2, bq, bk, x2t, kt);

    sqnorm_k<<<dim3(144, NB, 2), dim3(64, 4), 0, stream>>>(x2t, kt, nq, nk);
    boxinv_k<<<18, 256, 0, stream>>>(nk, nq, invNk, invNq);

    // gram split-K2 -> Mpart (648 blocks)
    gram_k<<<dim3(9, 9, 8), 256, 0, stream>>>(kt, x2t, Mpart);

    argmax1_k<<<dim3(9, 24, NB), dim3(64, 4), 0, stream>>>(Mpart, invNk, Pv, Pi);
    argmax2_k<<<9, 256, 0, stream>>>(Pv, Pi, invNq, Sbuf, Arg);

    gather_k<<<dim3(144, NB), dim3(64, 4), 0, stream>>>(kt, Arg, x2t);

    wcast_k<<<8192, 256, 0, stream>>>(wt, wtb);
    // final fused conv (576 blocks)
    fin_k<<<dim3(9, 16, 4), 256, 0, stream>>>(wtb, x2t, bt, Sbuf, part_tgt, out);
}

// Round 5
// 365.370 us; speedup vs baseline: 4.8428x; 1.0561x over previous
//
#include <hip/hip_runtime.h>
#include <cstddef>
#include <cstdint>

#define LPIX 576
#define CCH  2048
#define NB   4

typedef __attribute__((ext_vector_type(8))) short short8;
typedef __attribute__((ext_vector_type(4))) float f32x4;
typedef __attribute__((ext_vector_type(4))) unsigned short u16x4;

__device__ __forceinline__ unsigned short f2bf(float f) {
    uint32_t u = __builtin_bit_cast(uint32_t, f);
    u += 0x7fff + ((u >> 16) & 1);          // round-to-nearest-even
    return (unsigned short)(u >> 16);
}
__device__ __forceinline__ float bf2f(unsigned short s) {
    return __builtin_bit_cast(float, (uint32_t)s << 16);
}

__device__ __forceinline__ void gload_lds16(const void* g, void* l) {
    __builtin_amdgcn_global_load_lds((const __attribute__((address_space(1))) void*)g,
                                     (__attribute__((address_space(3))) void*)l, 16, 0, 0);
}

// ---------------- MFMA K-loop, BK=64 twin 32-k panels ----------------
// D[m][n] += A[m][k]*B[n][k], bf16, k-contiguous. 256 threads = 4 waves (2x2).
// LDS: As[BM*64], Bs[BN*64] shorts, organized [panel(2)][rows][32].
// Per refill: BM/32+BN/32 gload16 per thread, 2*(BM/32)*(BN/32) MFMAs, 2 barriers.
template<int BM, int BN>
__device__ __forceinline__ void mm_core64(
    const short* __restrict__ Ab, int lda,
    const short* __restrict__ Bb, int ldb,
    int k0, int kend, short* As, short* Bs,
    int m0, int n0, f32x4 (&acc)[BM/32][BN/32])
{
    const int tid  = threadIdx.x;
    const int lane = tid & 63;
    const int w    = tid >> 6;
    const int wm = (w & 1) * (BM / 2);
    const int wn = (w >> 1) * (BN / 2);
    const int l15 = lane & 15;
    const int k8  = (lane >> 4) * 8;
    const int r   = tid >> 2;          // 0..63
    const int kk  = (tid & 3) * 8;     // 0,8,16,24 within a 32-k panel

    const short* Aptr[BM / 32]; short* Alds[BM / 32];
    #pragma unroll
    for (int u = 0; u < BM / 32; ++u) {
        const int p = u & 1, g = u >> 1;
        Aptr[u] = Ab + (size_t)(m0 + g * 64 + r) * lda + p * 32 + kk;
        Alds[u] = As + p * BM * 32 + g * 2048 + tid * 8;
    }
    const short* Bptr[BN / 32]; short* Blds[BN / 32];
    #pragma unroll
    for (int u = 0; u < BN / 32; ++u) {
        const int p = u & 1, g = u >> 1;
        Bptr[u] = Bb + (size_t)(n0 + g * 64 + r) * ldb + p * 32 + kk;
        Blds[u] = Bs + p * BN * 32 + g * 2048 + tid * 8;
    }

    for (int c0 = k0; c0 < kend; c0 += 64) {
        #pragma unroll
        for (int u = 0; u < BM / 32; ++u) gload_lds16(Aptr[u] + c0, Alds[u]);
        #pragma unroll
        for (int u = 0; u < BN / 32; ++u) gload_lds16(Bptr[u] + c0, Blds[u]);
        __syncthreads();
        #pragma unroll
        for (int s = 0; s < 2; ++s) {
            short8 fa[BM / 32], fb[BN / 32];
            #pragma unroll
            for (int i = 0; i < BM / 32; ++i)
                fa[i] = *(const short8*)(As + s * BM * 32 + (wm + i * 16 + l15) * 32 + k8);
            #pragma unroll
            for (int j = 0; j < BN / 32; ++j)
                fb[j] = *(const short8*)(Bs + s * BN * 32 + (wn + j * 16 + l15) * 32 + k8);
            #pragma unroll
            for (int i = 0; i < BM / 32; ++i)
                #pragma unroll
                for (int j = 0; j < BN / 32; ++j)
                    acc[i][j] = __builtin_amdgcn_mfma_f32_16x16x32_bf16(fa[i], fb[j], acc[i][j], 0, 0, 0);
        }
        __syncthreads();
    }
}

// ---------------- both weight casts in one dispatch ----------------
__global__ __launch_bounds__(256) void wcast2_k(const float* __restrict__ wq,
                                                const float* __restrict__ wk,
                                                short* __restrict__ Wb) {
    const float* W = blockIdx.y ? wk : wq;
    short* D = Wb + (size_t)blockIdx.y * CCH * CCH;
    int i = (blockIdx.x * 256 + threadIdx.x) * 4;
    float4 v = *(const float4*)(W + i);
    u16x4 u;
    u.x = f2bf(v.x); u.y = f2bf(v.y); u.z = f2bf(v.z); u.w = f2bf(v.w);
    *(u16x4*)(D + i) = u;
}

__global__ __launch_bounds__(256) void wcast_k(const float* __restrict__ W,
                                               short* __restrict__ Wb) {
    int i = (blockIdx.x * 256 + threadIdx.x) * 4;
    float4 v = *(const float4*)(W + i);
    u16x4 u;
    u.x = f2bf(v.x); u.y = f2bf(v.y); u.z = f2bf(v.z); u.w = f2bf(v.w);
    *(u16x4*)(Wb + i) = u;
}

// ---------------- merged transpose-cast: tgt & ref [b][c][l] fp32 -> T1[which][b][l][c] bf16 ----
__global__ __launch_bounds__(256) void tcast_k(const float* __restrict__ tgt,
                                               const float* __restrict__ ref,
                                               short* __restrict__ T1) {
    __shared__ float tile[32][33];
    const int z = blockIdx.z;
    const int b = z & 3, which = z >> 2;
    const float* X = (which ? ref : tgt) + (size_t)b * CCH * LPIX;
    const int c0 = blockIdx.y * 32;
    const int l0 = blockIdx.x * 32;
    const int tx = threadIdx.x, ty = threadIdx.y;
    #pragma unroll
    for (int j = 0; j < 4; ++j)
        tile[ty + j * 8][tx] = X[(size_t)(c0 + ty + j * 8) * LPIX + l0 + tx];
    __syncthreads();
    short* D = T1 + ((size_t)(which * NB + b) * LPIX) * CCH;
    #pragma unroll
    for (int j = 0; j < 4; ++j)
        D[(size_t)(l0 + ty + j * 8) * CCH + c0 + tx] = (short)f2bf(tile[tx][ty + j * 8]);
}

// ---------------- merged q/k conv: 64(l) x 128(o) tiles, z = b*2+which ----------------
__global__ __launch_bounds__(256) void conv_k(
    const short* __restrict__ T1, const short* __restrict__ Wb,
    const float* __restrict__ bq, const float* __restrict__ bk,
    short* __restrict__ x2t, short* __restrict__ kt)
{
    __shared__ short As[64 * 64];
    __shared__ short Bs[128 * 64];
    const int z = blockIdx.z;
    const int b = z >> 1, which = z & 1;
    const short* Ab = T1 + (size_t)(which * NB + b) * LPIX * CCH;
    const short* Bb = Wb + (size_t)which * CCH * CCH;
    const float* bias = which ? bk : bq;
    short* Yb = which ? (kt + (size_t)b * LPIX * CCH) : (x2t + (size_t)b * LPIX * 4096);
    const int ldy = which ? CCH : 4096;
    const int m0 = blockIdx.y * 64;    // l
    const int n0 = blockIdx.x * 128;   // o
    f32x4 acc[2][4] = {};
    mm_core64<64, 128>(Ab, CCH, Bb, CCH, 0, CCH, As, Bs, m0, n0, acc);
    const int lane = threadIdx.x & 63, w = threadIdx.x >> 6;
    const int wm = (w & 1) * 32, wn = (w >> 1) * 64;
    const int l15 = lane & 15, quad = lane >> 4;
    #pragma unroll
    for (int i = 0; i < 2; ++i)
        #pragma unroll
        for (int j = 0; j < 4; ++j) {
            const int gn = n0 + wn + j * 16 + l15;
            const float bi = bias[gn];
            #pragma unroll
            for (int r = 0; r < 4; ++r) {
                const int gm = m0 + wm + i * 16 + quad * 4 + r;
                Yb[(size_t)gm * ldy + gn] = (short)f2bf(acc[i][j][r] + bi);
            }
        }
}

// ---------------- gram with split-K2: M_part[kc][b][lr][lt], 64x64 tiles ----------------
__global__ __launch_bounds__(256) void gram_k(
    const short* __restrict__ kt, const short* __restrict__ x2t,
    float* __restrict__ Mpart)
{
    __shared__ short As[64 * 64];
    __shared__ short Bs[64 * 64];
    const int z = blockIdx.z;
    const int b = z >> 1, kc = z & 1;
    const short* Ab = kt + (size_t)b * LPIX * CCH;
    const short* Bb = x2t + (size_t)b * LPIX * 4096;
    const int m0 = blockIdx.y * 64;   // lr
    const int n0 = blockIdx.x * 64;   // lt
    f32x4 acc[2][2] = {};
    mm_core64<64, 64>(Ab, CCH, Bb, 4096, kc * 1024, kc * 1024 + 1024, As, Bs, m0, n0, acc);
    float* Mb = Mpart + (size_t)(kc * NB + b) * LPIX * LPIX;
    const int lane = threadIdx.x & 63, w = threadIdx.x >> 6;
    const int wm = (w & 1) * 32, wn = (w >> 1) * 32;
    const int l15 = lane & 15, quad = lane >> 4;
    #pragma unroll
    for (int i = 0; i < 2; ++i)
        #pragma unroll
        for (int j = 0; j < 2; ++j) {
            const int gn = n0 + wn + j * 16 + l15;
            #pragma unroll
            for (int r = 0; r < 4; ++r) {
                const int gm = m0 + wm + i * 16 + quad * 4 + r;
                Mb[(size_t)gm * LPIX + gn] = acc[i][j][r];
            }
        }
}

// ---------------- final: 128(o) x 64(l), epilogue bias + *S + PT ----------------
__global__ __launch_bounds__(256) void fin_k(
    const short* __restrict__ wtb, const short* __restrict__ x2t,
    const float* __restrict__ bt, const float* __restrict__ S,
    const float* __restrict__ PT, float* __restrict__ out)
{
    __shared__ short As[128 * 64];
    __shared__ short Bs[64 * 64];
    const int b = blockIdx.z;
    const short* Bb = x2t + (size_t)b * LPIX * 4096;
    const int m0 = blockIdx.y * 128;  // o
    const int n0 = blockIdx.x * 64;   // l
    f32x4 acc[4][2] = {};
    mm_core64<128, 64>(wtb, 4096, Bb, 4096, 0, 4096, As, Bs, m0, n0, acc);
    const int lane = threadIdx.x & 63, w = threadIdx.x >> 6;
    const int wm = (w & 1) * 64, wn = (w >> 1) * 32;
    const int l15 = lane & 15, quad = lane >> 4;
    #pragma unroll
    for (int i = 0; i < 4; ++i)
        #pragma unroll
        for (int j = 0; j < 2; ++j) {
            const int gn = n0 + wn + j * 16 + l15;
            const float sv = S[b * LPIX + gn];
            #pragma unroll
            for (int r = 0; r < 4; ++r) {
                const int gm = m0 + wm + i * 16 + quad * 4 + r;
                float v = (acc[i][j][r] + bt[gm]) * sv
                        + PT[((size_t)b * CCH + gm) * LPIX + gn];
                out[((size_t)b * CCH + gm) * LPIX + gn] = v;
            }
        }
}

// ---------------- per-pixel squared channel norms (bf16 inputs) ----------------
__global__ __launch_bounds__(256) void sqnorm_k(
    const short* __restrict__ qt, const short* __restrict__ kt,
    float* __restrict__ nq, float* __restrict__ nk)
{
    const int b = blockIdx.y;
    const int l = blockIdx.x * 4 + threadIdx.y;
    const int lane = threadIdx.x;
    const int z = blockIdx.z;
    const short* src = z ? (kt + ((size_t)b * LPIX + l) * CCH)
                         : (qt + ((size_t)b * LPIX + l) * 4096);
    float s = 0.f;
    #pragma unroll
    for (int j = 0; j < 8; ++j) {
        u16x4 u = *(const u16x4*)(src + (lane + j * 64) * 4);
        float a = bf2f(u.x), c = bf2f(u.y), d = bf2f(u.z), e = bf2f(u.w);
        s += a * a + c * c + d * d + e * e;
    }
    #pragma unroll
    for (int off = 32; off > 0; off >>= 1)
        s += __shfl_down(s, off);
    if (lane == 0) (z ? nk : nq)[b * LPIX + l] = s;
}

// ---------------- 3x3 box filter + inverse sqrt of patch norms ----------------
__global__ void boxinv_k(const float* __restrict__ nk, const float* __restrict__ nq,
                         float* __restrict__ invNk, float* __restrict__ invNq)
{
    int idx = blockIdx.x * 256 + threadIdx.x;
    if (idx >= 2 * NB * LPIX) return;
    int map = idx / (NB * LPIX);
    int rem = idx % (NB * LPIX);
    int b = rem / LPIX, l = rem % LPIX;
    int i = l / 24, j = l % 24;
    const float* src = map ? nq : nk;
    float s = 0.f;
    for (int di = -1; di <= 1; ++di)
        for (int dj = -1; dj <= 1; ++dj) {
            int ii = i + di, jj = j + dj;
            if (ii >= 0 && ii < 24 && jj >= 0 && jj < 24)
                s += src[b * LPIX + ii * 24 + jj];
        }
    float n = fmaxf(sqrtf(s), 1e-12f);
    (map ? invNq : invNk)[b * LPIX + l] = 1.0f / n;
}

// ---------------- stage 1: 9-tap aggregation (sum of 2 K-partials) + chunk argmax ----
__global__ __launch_bounds__(256) void argmax1_k(
    const float* __restrict__ Mpart, const float* __restrict__ invNk,
    float* __restrict__ Pv, int* __restrict__ Pi)
{
    const int b   = blockIdx.z;
    const int lrb = blockIdx.y;                 // 0..23, chunk of 24 lr rows
    const int tx = threadIdx.x, ty = threadIdx.y;
    const int lt = blockIdx.x * 64 + tx;
    const int it = lt / 24, jt = lt % 24;
    const float* Mb0 = Mpart + (size_t)b * LPIX * LPIX;
    const float* Mb1 = Mpart + (size_t)(NB + b) * LPIX * LPIX;
    float best = -1e30f; int bidx = 0;
    #pragma unroll
    for (int i = 0; i < 6; ++i) {
        const int lr = lrb * 24 + ty + i * 4;
        const int ir = lr / 24, jr = lr % 24;
        const int base = lr * LPIX + lt;
        float g = 0.f;
        #pragma unroll
        for (int di = -1; di <= 1; ++di) {
            if ((unsigned)(ir + di) > 23u || (unsigned)(it + di) > 23u) continue;
            #pragma unroll
            for (int dj = -1; dj <= 1; ++dj) {
                if ((unsigned)(jr + dj) > 23u || (unsigned)(jt + dj) > 23u) continue;
                const int o = base + (di * 24 + dj) * (LPIX + 1);
                g += Mb0[o] + Mb1[o];
            }
        }
        float v = g * invNk[b * LPIX + lr];
        if (v > best) { best = v; bidx = lr; }
    }
    __shared__ float rv[4][64];
    __shared__ int   ri[4][64];
    rv[ty][tx] = best; ri[ty][tx] = bidx;
    __syncthreads();
    if (ty == 0) {
        #pragma unroll
        for (int y = 1; y < 4; ++y) {
            float v = rv[y][tx]; int id = ri[y][tx];
            if (v > best || (v == best && id < bidx)) { best = v; bidx = id; }
        }
        Pv[((size_t)b * 24 + lrb) * LPIX + lt] = best;
        Pi[((size_t)b * 24 + lrb) * LPIX + lt] = bidx;
    }
}

// ---------------- stage 2: fold 24 partials (ascending lr -> first-max ties) ----------
__global__ __launch_bounds__(256) void argmax2_k(
    const float* __restrict__ Pv, const int* __restrict__ Pi,
    const float* __restrict__ invNq,
    float* __restrict__ S, int* __restrict__ Arg)
{
    int idx = blockIdx.x * 256 + threadIdx.x;
    if (idx >= NB * LPIX) return;
    int b = idx / LPIX, lt = idx % LPIX;
    float best = -1e30f; int bidx = 0;
    #pragma unroll
    for (int c = 0; c < 24; ++c) {
        float v = Pv[((size_t)b * 24 + c) * LPIX + lt];
        int  id = Pi[((size_t)b * 24 + c) * LPIX + lt];
        if (v > best || (v == best && id < bidx)) { best = v; bidx = id; }
    }
    S[idx]   = best * invNq[idx];
    Arg[idx] = bidx;
}

// ---------------- gather best ref patches + fold (overlap-add /9) -> x2t[:,2048:] ----
__global__ __launch_bounds__(256) void gather_k(
    const short* __restrict__ kt, const int* __restrict__ Arg,
    short* __restrict__ x2t)
{
    const int b = blockIdx.y;
    const int l0 = blockIdx.x * 4;
    const int lane = threadIdx.x, ty = threadIdx.y;
    const int tid = ty * 64 + lane;
    __shared__ int tap[4][9];
    if (tid < 36) {
        int px = tid / 9, t9 = tid % 9;
        int l = l0 + px;
        int i = l / 24, j = l % 24;
        int ki = t9 / 3, kj = t9 % 3;
        int ip = i + 1 - ki, jp = j + 1 - kj;
        int off = -1;
        if (ip >= 0 && ip < 24 && jp >= 0 && jp < 24) {
            int a = Arg[b * LPIX + ip * 24 + jp];
            int rr = a / 24 + ki - 1;
            int cc = a % 24 + kj - 1;
            if (rr >= 0 && rr < 24 && cc >= 0 && cc < 24) off = rr * 24 + cc;
        }
        tap[px][t9] = off;
    }
    __syncthreads();
    const int l = l0 + ty;
    const short* Kb = kt + (size_t)b * LPIX * CCH;
    short* dst = x2t + ((size_t)b * LPIX + l) * 4096 + CCH;
    int t[9];
    #pragma unroll
    for (int i = 0; i < 9; ++i) t[i] = tap[ty][i];
    const float inv9 = 1.0f / 9.0f;
    #pragma unroll
    for (int j = 0; j < 8; ++j) {
        int c = (lane + j * 64) * 4;
        float s0 = 0.f, s1 = 0.f, s2 = 0.f, s3 = 0.f;
        #pragma unroll
        for (int t9 = 0; t9 < 9; ++t9) {
            int off = t[t9];
            if (off < 0) continue;
            u16x4 u = *(const u16x4*)(Kb + (size_t)off * CCH + c);
            s0 += bf2f(u.x); s1 += bf2f(u.y); s2 += bf2f(u.z); s3 += bf2f(u.w);
        }
        u16x4 o;
        o.x = f2bf(s0 * inv9); o.y = f2bf(s1 * inv9);
        o.z = f2bf(s2 * inv9); o.w = f2bf(s3 * inv9);
        *(u16x4*)(dst + c) = o;
    }
}

extern "C" void kernel_launch(void* const* d_in, const int* in_sizes, int n_in,
                              void* d_out, int out_size, void* d_ws, size_t ws_size,
                              hipStream_t stream) {
    const float* part_ref = (const float*)d_in[0];
    const float* part_tgt = (const float*)d_in[1];
    const float* wq = (const float*)d_in[2];
    const float* bq = (const float*)d_in[3];
    const float* wk = (const float*)d_in[4];
    const float* bk = (const float*)d_in[5];
    const float* wt = (const float*)d_in[6];
    const float* bt = (const float*)d_in[7];
    float* out = (float*)d_out;

    // ws layout (shorts unless noted): wqb2 (2x C*C, reused as wtb) | T1 (2x NB*576*2048,
    // reused as Mpart fp32) | kt | x2t | small fp32
    short* wqb2 = (short*)d_ws;
    short* wtb  = wqb2;                                       // reuse after convs
    short* T1   = wqb2 + (size_t)2 * CCH * CCH;
    short* kt   = T1 + (size_t)2 * NB * LPIX * CCH;
    short* x2t  = kt + (size_t)NB * LPIX * CCH;
    float* Mpart = (float*)T1;                                // 2*NB*576*576 fp32 = 10.6MB <= T1 18.9MB
    float* nk    = (float*)(x2t + (size_t)NB * LPIX * 4096);
    float* nq    = nk + NB * LPIX;
    float* invNk = nq + NB * LPIX;
    float* invNq = invNk + NB * LPIX;
    float* Sbuf  = invNq + NB * LPIX;
    int*   Arg   = (int*)(Sbuf + NB * LPIX);
    float* Pv    = (float*)(Arg + NB * LPIX);                 // 24*NB*LPIX
    int*   Pi    = (int*)(Pv + (size_t)24 * NB * LPIX);

    wcast2_k<<<dim3(4096, 2), 256, 0, stream>>>(wq, wk, wqb2);
    tcast_k<<<dim3(18, 64, 8), dim3(32, 8), 0, stream>>>(part_tgt, part_ref, T1);

    // q -> x2t[:, :, 0:2048]; k -> kt   (one dispatch, 1152 blocks)
    conv_k<<<dim3(16, 9, 8), 256, 0, stream>>>(T1, wqb2, bq, bk, x2t, kt);

    sqnorm_k<<<dim3(144, NB, 2), dim3(64, 4), 0, stream>>>(x2t, kt, nq, nk);
    boxinv_k<<<18, 256, 0, stream>>>(nk, nq, invNk, invNq);

    // gram split-K2 -> Mpart (648 blocks)
    gram_k<<<dim3(9, 9, 8), 256, 0, stream>>>(kt, x2t, Mpart);

    argmax1_k<<<dim3(9, 24, NB), dim3(64, 4), 0, stream>>>(Mpart, invNk, Pv, Pi);
    argmax2_k<<<9, 256, 0, stream>>>(Pv, Pi, invNq, Sbuf, Arg);

    gather_k<<<dim3(144, NB), dim3(64, 4), 0, stream>>>(kt, Arg, x2t);

    wcast_k<<<8192, 256, 0, stream>>>(wt, wtb);
    // final fused conv (576 blocks)
    fin_k<<<dim3(9, 16, 4), 256, 0, stream>>>(wtb, x2t, bt, Sbuf, part_tgt, out);
}

// Round 6
// 351.604 us; speedup vs baseline: 5.0324x; 1.0392x over previous
//
#include <hip/hip_runtime.h>
#include <cstddef>
#include <cstdint>

#define LPIX 576
#define CCH  2048
#define NB   4

typedef __attribute__((ext_vector_type(8))) short short8;
typedef __attribute__((ext_vector_type(4))) float f32x4;
typedef __attribute__((ext_vector_type(4))) unsigned short u16x4;

__device__ __forceinline__ unsigned short f2bf(float f) {
    uint32_t u = __builtin_bit_cast(uint32_t, f);
    u += 0x7fff + ((u >> 16) & 1);          // round-to-nearest-even
    return (unsigned short)(u >> 16);
}
__device__ __forceinline__ float bf2f(unsigned short s) {
    return __builtin_bit_cast(float, (uint32_t)s << 16);
}

__device__ __forceinline__ void gload_lds16(const void* g, void* l) {
    __builtin_amdgcn_global_load_lds((const __attribute__((address_space(1))) void*)g,
                                     (__attribute__((address_space(3))) void*)l, 16, 0, 0);
}

// ---------------- MFMA K-loop, BK=64 twin 32-k panels ----------------
template<int BM, int BN>
__device__ __forceinline__ void mm_core64(
    const short* __restrict__ Ab, int lda,
    const short* __restrict__ Bb, int ldb,
    int k0, int kend, short* As, short* Bs,
    int m0, int n0, f32x4 (&acc)[BM/32][BN/32])
{
    const int tid  = threadIdx.x;
    const int lane = tid & 63;
    const int w    = tid >> 6;
    const int wm = (w & 1) * (BM / 2);
    const int wn = (w >> 1) * (BN / 2);
    const int l15 = lane & 15;
    const int k8  = (lane >> 4) * 8;
    const int r   = tid >> 2;          // 0..63
    const int kk  = (tid & 3) * 8;     // 0,8,16,24 within a 32-k panel

    const short* Aptr[BM / 32]; short* Alds[BM / 32];
    #pragma unroll
    for (int u = 0; u < BM / 32; ++u) {
        const int p = u & 1, g = u >> 1;
        Aptr[u] = Ab + (size_t)(m0 + g * 64 + r) * lda + p * 32 + kk;
        Alds[u] = As + p * BM * 32 + g * 2048 + tid * 8;
    }
    const short* Bptr[BN / 32]; short* Blds[BN / 32];
    #pragma unroll
    for (int u = 0; u < BN / 32; ++u) {
        const int p = u & 1, g = u >> 1;
        Bptr[u] = Bb + (size_t)(n0 + g * 64 + r) * ldb + p * 32 + kk;
        Blds[u] = Bs + p * BN * 32 + g * 2048 + tid * 8;
    }

    for (int c0 = k0; c0 < kend; c0 += 64) {
        #pragma unroll
        for (int u = 0; u < BM / 32; ++u) gload_lds16(Aptr[u] + c0, Alds[u]);
        #pragma unroll
        for (int u = 0; u < BN / 32; ++u) gload_lds16(Bptr[u] + c0, Blds[u]);
        __syncthreads();
        #pragma unroll
        for (int s = 0; s < 2; ++s) {
            short8 fa[BM / 32], fb[BN / 32];
            #pragma unroll
            for (int i = 0; i < BM / 32; ++i)
                fa[i] = *(const short8*)(As + s * BM * 32 + (wm + i * 16 + l15) * 32 + k8);
            #pragma unroll
            for (int j = 0; j < BN / 32; ++j)
                fb[j] = *(const short8*)(Bs + s * BN * 32 + (wn + j * 16 + l15) * 32 + k8);
            #pragma unroll
            for (int i = 0; i < BM / 32; ++i)
                #pragma unroll
                for (int j = 0; j < BN / 32; ++j)
                    acc[i][j] = __builtin_amdgcn_mfma_f32_16x16x32_bf16(fa[i], fb[j], acc[i][j], 0, 0, 0);
        }
        __syncthreads();
    }
}

// ---------------- both conv weight casts in one dispatch ----------------
__global__ __launch_bounds__(256) void wcast2_k(const float* __restrict__ wq,
                                                const float* __restrict__ wk,
                                                short* __restrict__ Wb) {
    const float* W = blockIdx.y ? wk : wq;
    short* D = Wb + (size_t)blockIdx.y * CCH * CCH;
    int i = (blockIdx.x * 256 + threadIdx.x) * 4;
    float4 v = *(const float4*)(W + i);
    u16x4 u;
    u.x = f2bf(v.x); u.y = f2bf(v.y); u.z = f2bf(v.z); u.w = f2bf(v.w);
    *(u16x4*)(D + i) = u;
}

__global__ __launch_bounds__(256) void wcast_k(const float* __restrict__ W,
                                               short* __restrict__ Wb) {
    int i = (blockIdx.x * 256 + threadIdx.x) * 4;
    float4 v = *(const float4*)(W + i);
    u16x4 u;
    u.x = f2bf(v.x); u.y = f2bf(v.y); u.z = f2bf(v.z); u.w = f2bf(v.w);
    *(u16x4*)(Wb + i) = u;
}

// ---------------- merged transpose-cast: tgt & ref [b][c][l] fp32 -> T1[which][b][l][c] bf16 ----
__global__ __launch_bounds__(256) void tcast_k(const float* __restrict__ tgt,
                                               const float* __restrict__ ref,
                                               short* __restrict__ T1) {
    __shared__ float tile[32][33];
    const int z = blockIdx.z;
    const int b = z & 3, which = z >> 2;
    const float* X = (which ? ref : tgt) + (size_t)b * CCH * LPIX;
    const int c0 = blockIdx.y * 32;
    const int l0 = blockIdx.x * 32;
    const int tx = threadIdx.x, ty = threadIdx.y;
    #pragma unroll
    for (int j = 0; j < 4; ++j)
        tile[ty + j * 8][tx] = X[(size_t)(c0 + ty + j * 8) * LPIX + l0 + tx];
    __syncthreads();
    short* D = T1 + ((size_t)(which * NB + b) * LPIX) * CCH;
    #pragma unroll
    for (int j = 0; j < 4; ++j)
        D[(size_t)(l0 + ty + j * 8) * CCH + c0 + tx] = (short)f2bf(tile[tx][ty + j * 8]);
}

// ---------------- merged q/k conv, XCD-swizzled, fused channel-sqnorm atomics ----------
// 1D grid 1152: xcd=id&7 owns 4 weight slabs (2 MB, L2-resident)
__global__ __launch_bounds__(256) void conv_k(
    const short* __restrict__ T1, const short* __restrict__ Wb,
    const float* __restrict__ bq, const float* __restrict__ bk,
    short* __restrict__ x2t, short* __restrict__ kt,
    float* __restrict__ nq, float* __restrict__ nk)
{
    __shared__ short As[64 * 64];
    __shared__ short Bs[128 * 64];
    const int id = blockIdx.x;
    const int xcd = id & 7, slot = id >> 3;          // slot 0..143
    const int sid = xcd * 4 + slot / 36;             // weight slab 0..31
    const int r36 = slot % 36;
    const int which = sid >> 4;
    const int m0 = (r36 % 9) * 64;                   // l
    const int n0 = (sid & 15) * 128;                 // o
    const int b  = r36 / 9;
    const short* Ab = T1 + (size_t)(which * NB + b) * LPIX * CCH;
    const short* Bb = Wb + (size_t)which * CCH * CCH;
    const float* bias = which ? bk : bq;
    short* Yb = which ? (kt + (size_t)b * LPIX * CCH) : (x2t + (size_t)b * LPIX * 4096);
    float* Nb = (which ? nk : nq) + b * LPIX;
    const int ldy = which ? CCH : 4096;
    f32x4 acc[2][4] = {};
    mm_core64<64, 128>(Ab, CCH, Bb, CCH, 0, CCH, As, Bs, m0, n0, acc);
    const int lane = threadIdx.x & 63, w = threadIdx.x >> 6;
    const int wm = (w & 1) * 32, wn = (w >> 1) * 64;
    const int l15 = lane & 15, quad = lane >> 4;
    float pv[2][4] = {};
    #pragma unroll
    for (int i = 0; i < 2; ++i)
        #pragma unroll
        for (int j = 0; j < 4; ++j) {
            const int gn = n0 + wn + j * 16 + l15;
            const float bi = bias[gn];
            #pragma unroll
            for (int r = 0; r < 4; ++r) {
                const int gm = m0 + wm + i * 16 + quad * 4 + r;
                float v = acc[i][j][r] + bi;
                pv[i][r] += v * v;
                Yb[(size_t)gm * ldy + gn] = (short)f2bf(v);
            }
        }
    // reduce pv over the 16 lanes sharing (i,quad,r), then atomic into norm buffer
    #pragma unroll
    for (int i = 0; i < 2; ++i)
        #pragma unroll
        for (int r = 0; r < 4; ++r) {
            float s = pv[i][r];
            #pragma unroll
            for (int m = 1; m < 16; m <<= 1) s += __shfl_xor(s, m);
            if (l15 == 0) {
                const int gm = m0 + wm + i * 16 + quad * 4 + r;
                atomicAdd(&Nb[gm], s);
            }
        }
}

// ---------------- gram with split-K2: M_part[kc][b][lr][lt], 64x64 tiles ----------------
__global__ __launch_bounds__(256) void gram_k(
    const short* __restrict__ kt, const short* __restrict__ x2t,
    float* __restrict__ Mpart)
{
    __shared__ short As[64 * 64];
    __shared__ short Bs[64 * 64];
    const int z = blockIdx.z;
    const int b = z >> 1, kc = z & 1;
    const short* Ab = kt + (size_t)b * LPIX * CCH;
    const short* Bb = x2t + (size_t)b * LPIX * 4096;
    const int m0 = blockIdx.y * 64;   // lr
    const int n0 = blockIdx.x * 64;   // lt
    f32x4 acc[2][2] = {};
    mm_core64<64, 64>(Ab, CCH, Bb, 4096, kc * 1024, kc * 1024 + 1024, As, Bs, m0, n0, acc);
    float* Mb = Mpart + (size_t)(kc * NB + b) * LPIX * LPIX;
    const int lane = threadIdx.x & 63, w = threadIdx.x >> 6;
    const int wm = (w & 1) * 32, wn = (w >> 1) * 32;
    const int l15 = lane & 15, quad = lane >> 4;
    #pragma unroll
    for (int i = 0; i < 2; ++i)
        #pragma unroll
        for (int j = 0; j < 2; ++j) {
            const int gn = n0 + wn + j * 16 + l15;
            #pragma unroll
            for (int r = 0; r < 4; ++r) {
                const int gm = m0 + wm + i * 16 + quad * 4 + r;
                Mb[(size_t)gm * LPIX + gn] = acc[i][j][r];
            }
        }
}

// ---------------- final: 128(o) x 64(l), XCD-swizzled, epilogue bias + *S + PT ----------
// 1D grid 576: xcd owns 2 o-tiles (2 MB weights, L2-resident)
__global__ __launch_bounds__(256) void fin_k(
    const short* __restrict__ wtb, const short* __restrict__ x2t,
    const float* __restrict__ bt, const float* __restrict__ S,
    const float* __restrict__ PT, float* __restrict__ out)
{
    __shared__ short As[128 * 64];
    __shared__ short Bs[64 * 64];
    const int id = blockIdx.x;
    const int xcd = id & 7, slot = id >> 3;          // slot 0..71
    const int hi = slot >= 36;
    const int r36 = slot - hi * 36;
    const int m0 = (xcd * 2 + hi) * 128;             // o
    const int n0 = (r36 % 9) * 64;                   // l
    const int b  = r36 / 9;
    const short* Bb = x2t + (size_t)b * LPIX * 4096;
    f32x4 acc[4][2] = {};
    mm_core64<128, 64>(wtb, 4096, Bb, 4096, 0, 4096, As, Bs, m0, n0, acc);
    const int lane = threadIdx.x & 63, w = threadIdx.x >> 6;
    const int wm = (w & 1) * 64, wn = (w >> 1) * 32;
    const int l15 = lane & 15, quad = lane >> 4;
    #pragma unroll
    for (int i = 0; i < 4; ++i)
        #pragma unroll
        for (int j = 0; j < 2; ++j) {
            const int gn = n0 + wn + j * 16 + l15;
            const float sv = S[b * LPIX + gn];
            #pragma unroll
            for (int r = 0; r < 4; ++r) {
                const int gm = m0 + wm + i * 16 + quad * 4 + r;
                float v = (acc[i][j][r] + bt[gm]) * sv
                        + PT[((size_t)b * CCH + gm) * LPIX + gn];
                out[((size_t)b * CCH + gm) * LPIX + gn] = v;
            }
        }
}

// ---------------- stage 1: fused 3x3-box invNk + 9-tap aggregation + chunk argmax ----
__global__ __launch_bounds__(256) void argmax1_k(
    const float* __restrict__ Mpart, const float* __restrict__ nk,
    float* __restrict__ Pv, int* __restrict__ Pi)
{
    const int b   = blockIdx.z;
    const int lrb = blockIdx.y;                 // ir row 0..23
    const int tx = threadIdx.x, ty = threadIdx.y;
    const int tid = ty * 64 + tx;
    __shared__ float invNkS[24];
    if (tid < 24) {
        const int jr = tid;
        float s = 0.f;
        #pragma unroll
        for (int di = -1; di <= 1; ++di) {
            const int ii = lrb + di;
            if ((unsigned)ii > 23u) continue;
            #pragma unroll
            for (int dj = -1; dj <= 1; ++dj) {
                const int jj = jr + dj;
                if ((unsigned)jj > 23u) continue;
                s += nk[b * LPIX + ii * 24 + jj];
            }
        }
        invNkS[jr] = 1.0f / fmaxf(sqrtf(s), 1e-12f);
    }
    __syncthreads();
    const int lt = blockIdx.x * 64 + tx;
    const int it = lt / 24, jt = lt % 24;
    const float* Mb0 = Mpart + (size_t)b * LPIX * LPIX;
    const float* Mb1 = Mpart + (size_t)(NB + b) * LPIX * LPIX;
    float best = -1e30f; int bidx = 0;
    #pragma unroll
    for (int i = 0; i < 6; ++i) {
        const int jr = ty + i * 4;
        const int lr = lrb * 24 + jr;
        const int base = lr * LPIX + lt;
        float g = 0.f;
        #pragma unroll
        for (int di = -1; di <= 1; ++di) {
            if ((unsigned)(lrb + di) > 23u || (unsigned)(it + di) > 23u) continue;
            #pragma unroll
            for (int dj = -1; dj <= 1; ++dj) {
                if ((unsigned)(jr + dj) > 23u || (unsigned)(jt + dj) > 23u) continue;
                const int o = base + (di * 24 + dj) * (LPIX + 1);
                g += Mb0[o] + Mb1[o];
            }
        }
        float v = g * invNkS[jr];
        if (v > best) { best = v; bidx = lr; }
    }
    __shared__ float rv[4][64];
    __shared__ int   ri[4][64];
    rv[ty][tx] = best; ri[ty][tx] = bidx;
    __syncthreads();
    if (ty == 0) {
        #pragma unroll
        for (int y = 1; y < 4; ++y) {
            float v = rv[y][tx]; int id = ri[y][tx];
            if (v > best || (v == best && id < bidx)) { best = v; bidx = id; }
        }
        Pv[((size_t)b * 24 + lrb) * LPIX + lt] = best;
        Pi[((size_t)b * 24 + lrb) * LPIX + lt] = bidx;
    }
}

// ---------------- stage 2: fold 24 partials, fused invNq ----------------
__global__ __launch_bounds__(256) void argmax2_k(
    const float* __restrict__ Pv, const int* __restrict__ Pi,
    const float* __restrict__ nq,
    float* __restrict__ S, int* __restrict__ Arg)
{
    int idx = blockIdx.x * 256 + threadIdx.x;
    if (idx >= NB * LPIX) return;
    int b = idx / LPIX, lt = idx % LPIX;
    int it = lt / 24, jt = lt % 24;
    float s = 0.f;
    #pragma unroll
    for (int di = -1; di <= 1; ++di) {
        const int ii = it + di;
        if ((unsigned)ii > 23u) continue;
        #pragma unroll
        for (int dj = -1; dj <= 1; ++dj) {
            const int jj = jt + dj;
            if ((unsigned)jj > 23u) continue;
            s += nq[b * LPIX + ii * 24 + jj];
        }
    }
    const float invNq = 1.0f / fmaxf(sqrtf(s), 1e-12f);
    float best = -1e30f; int bidx = 0;
    #pragma unroll
    for (int c = 0; c < 24; ++c) {
        float v = Pv[((size_t)b * 24 + c) * LPIX + lt];
        int  id = Pi[((size_t)b * 24 + c) * LPIX + lt];
        if (v > best || (v == best && id < bidx)) { best = v; bidx = id; }
    }
    S[idx]   = best * invNq;
    Arg[idx] = bidx;
}

// ---------------- gather best ref patches + fold (/9), XCD-swizzled ----------------
// 1D grid 576: XCD pair owns one b (kt[b]=2.36 MB L2-resident)
__global__ __launch_bounds__(256) void gather_k(
    const short* __restrict__ kt, const int* __restrict__ Arg,
    short* __restrict__ x2t)
{
    const int id = blockIdx.x;
    const int xcd = id & 7, slot = id >> 3;          // slot 0..71
    const int b  = xcd >> 1;
    const int l0 = ((xcd & 1) * 72 + slot) * 4;
    const int lane = threadIdx.x, ty = threadIdx.y;
    const int tid = ty * 64 + lane;
    __shared__ int tap[4][9];
    if (tid < 36) {
        int px = tid / 9, t9 = tid % 9;
        int l = l0 + px;
        int i = l / 24, j = l % 24;
        int ki = t9 / 3, kj = t9 % 3;
        int ip = i + 1 - ki, jp = j + 1 - kj;
        int off = -1;
        if (ip >= 0 && ip < 24 && jp >= 0 && jp < 24) {
            int a = Arg[b * LPIX + ip * 24 + jp];
            int rr = a / 24 + ki - 1;
            int cc = a % 24 + kj - 1;
            if (rr >= 0 && rr < 24 && cc >= 0 && cc < 24) off = rr * 24 + cc;
        }
        tap[px][t9] = off;
    }
    __syncthreads();
    const int l = l0 + ty;
    const short* Kb = kt + (size_t)b * LPIX * CCH;
    short* dst = x2t + ((size_t)b * LPIX + l) * 4096 + CCH;
    int t[9];
    #pragma unroll
    for (int i = 0; i < 9; ++i) t[i] = tap[ty][i];
    const float inv9 = 1.0f / 9.0f;
    #pragma unroll
    for (int j = 0; j < 8; ++j) {
        int c = (lane + j * 64) * 4;
        float s0 = 0.f, s1 = 0.f, s2 = 0.f, s3 = 0.f;
        #pragma unroll
        for (int t9 = 0; t9 < 9; ++t9) {
            int off = t[t9];
            if (off < 0) continue;
            u16x4 u = *(const u16x4*)(Kb + (size_t)off * CCH + c);
            s0 += bf2f(u.x); s1 += bf2f(u.y); s2 += bf2f(u.z); s3 += bf2f(u.w);
        }
        u16x4 o;
        o.x = f2bf(s0 * inv9); o.y = f2bf(s1 * inv9);
        o.z = f2bf(s2 * inv9); o.w = f2bf(s3 * inv9);
        *(u16x4*)(dst + c) = o;
    }
}

extern "C" void kernel_launch(void* const* d_in, const int* in_sizes, int n_in,
                              void* d_out, int out_size, void* d_ws, size_t ws_size,
                              hipStream_t stream) {
    const float* part_ref = (const float*)d_in[0];
    const float* part_tgt = (const float*)d_in[1];
    const float* wq = (const float*)d_in[2];
    const float* bq = (const float*)d_in[3];
    const float* wk = (const float*)d_in[4];
    const float* bk = (const float*)d_in[5];
    const float* wt = (const float*)d_in[6];
    const float* bt = (const float*)d_in[7];
    float* out = (float*)d_out;

    short* wqb2 = (short*)d_ws;
    short* wtb  = wqb2;                                       // reuse after convs
    short* T1   = wqb2 + (size_t)2 * CCH * CCH;
    short* kt   = T1 + (size_t)2 * NB * LPIX * CCH;
    short* x2t  = kt + (size_t)NB * LPIX * CCH;
    float* Mpart = (float*)T1;                                // aliases T1 (dead by gram time)
    float* nk    = (float*)(x2t + (size_t)NB * LPIX * 4096);
    float* nq    = nk + NB * LPIX;
    float* Sbuf  = nq + NB * LPIX;
    int*   Arg   = (int*)(Sbuf + NB * LPIX);
    float* Pv    = (float*)(Arg + NB * LPIX);                 // 24*NB*LPIX
    int*   Pi    = (int*)(Pv + (size_t)24 * NB * LPIX);

    hipMemsetAsync(nk, 0, 2 * NB * LPIX * sizeof(float), stream);  // nk|nq contiguous

    wcast2_k<<<dim3(4096, 2), 256, 0, stream>>>(wq, wk, wqb2);
    tcast_k<<<dim3(18, 64, 8), dim3(32, 8), 0, stream>>>(part_tgt, part_ref, T1);

    // q -> x2t[:, :, 0:2048]; k -> kt; fused channel-norm atomics (1152 blocks, swizzled)
    conv_k<<<1152, 256, 0, stream>>>(T1, wqb2, bq, bk, x2t, kt, nq, nk);

    // gram split-K2 -> Mpart (648 blocks)
    gram_k<<<dim3(9, 9, 8), 256, 0, stream>>>(kt, x2t, Mpart);

    argmax1_k<<<dim3(9, 24, NB), dim3(64, 4), 0, stream>>>(Mpart, nk, Pv, Pi);
    argmax2_k<<<9, 256, 0, stream>>>(Pv, Pi, nq, Sbuf, Arg);

    gather_k<<<576, dim3(64, 4), 0, stream>>>(kt, Arg, x2t);

    wcast_k<<<8192, 256, 0, stream>>>(wt, wtb);
    // final fused conv (576 blocks, swizzled)
    fin_k<<<576, 256, 0, stream>>>(wtb, x2t, bt, Sbuf, part_tgt, out);
}